// Round 1
// baseline (6076.100 us; speedup 1.0000x reference)
//
#include <hip/hip_runtime.h>
#include <math.h>

#define NGAUSS 50
#define NF 64
#define DIM 128
#define NPB 16

#define GSTEP (10.0f/49.0f)
#define GCOEFF (-0.5f/(GSTEP*GSTEP))
#define PIC (3.14159265358979323846f/10.0f)
#define LOG2F_ 0.69314718055994530942f

__device__ __forceinline__ float ssp_f(float x){
    // softplus(x) - log(2), numerically stable
    return fmaxf(x, 0.0f) + log1pf(__expf(-fabsf(x))) - LOG2F_;
}

// h = x @ conv_lin1_w   [N,128] @ [128,64] -> [N,64]
// one thread per (n,j); each wave covers one row n (j = lane) -> row loads
// are wave-uniform (scalar), weight loads coalesced.
extern "C" __global__ __launch_bounds__(256)
void k_lin1(const float* __restrict__ x, const float* __restrict__ w,
            float* __restrict__ h, int N)
{
    int idx = blockIdx.x * 256 + threadIdx.x;
    int n = idx >> 6, j = idx & 63;
    if (n >= N) return;
    const float* xr = x + (size_t)n * DIM;
    float acc = 0.0f;
    #pragma unroll 8
    for (int k = 0; k < DIM; k++) acc = fmaf(xr[k], w[k * NF + j], acc);
    h[(size_t)n * NF + j] = acc;
}

// Edge kernel: one thread per edge.
// Layer2 is fused as a rank-1 update inside layer1's j-loop so that every
// register array (ea[50], out[64]) is only ever statically indexed
// (dynamic indexing would spill to scratch). Weight addresses are
// wave-uniform (loop index only) -> scalar loads.
extern "C" __global__ __launch_bounds__(256)
void k_edge(const float* __restrict__ pos,
            const int*   __restrict__ ei,
            const float* __restrict__ w1, const float* __restrict__ b1,
            const float* __restrict__ w2, const float* __restrict__ b2,
            const float* __restrict__ h,
            float* __restrict__ agg, int E)
{
    int e = blockIdx.x * 256 + threadIdx.x;
    if (e >= E) return;
    int s = ei[e];
    int d = ei[E + e];

    float dx = pos[3*d]   - pos[3*s];
    float dy = pos[3*d+1] - pos[3*s+1];
    float dz = pos[3*d+2] - pos[3*s+2];
    float dist = sqrtf(dx*dx + dy*dy + dz*dz);

    // Gaussian smearing (static array, fully unrolled)
    float ea[NGAUSS];
    #pragma unroll
    for (int m = 0; m < NGAUSS; m++) {
        float t = dist - (float)m * GSTEP;
        ea[m] = __expf(GCOEFF * t * t);
    }

    // out = b2 + ssp(ea@w1 + b1) @ w2, computed as rank-1 updates
    float out[NF];
    #pragma unroll
    for (int j = 0; j < NF; j++) out[j] = b2[j];

    for (int j = 0; j < NF; j++) {            // dynamic, wave-uniform
        float acc = b1[j];
        const float* w1c = w1 + j;            // column j of [50,64]
        #pragma unroll
        for (int m = 0; m < NGAUSS; m++) acc = fmaf(ea[m], w1c[m * NF], acc);
        float hj = ssp_f(acc);
        const float* w2r = w2 + j * NF;       // row j of [64,64]
        #pragma unroll
        for (int j2 = 0; j2 < NF; j2++) out[j2] = fmaf(hj, w2r[j2], out[j2]);
    }

    float Cc = 0.5f * (__cosf(dist * PIC) + 1.0f);

    const float* hs = h + (size_t)s * NF;     // gather h[src] (L3-resident)
    float* ag = agg + (size_t)d * NF;
    #pragma unroll
    for (int j = 0; j < NF; j++) {
        atomicAdd(&ag[j], hs[j] * (out[j] * Cc));
    }
}

// Fused tail: h2 = ssp(agg@conv_lin2_w + b); h3 = h2@int_lin_w + b;
// out = x + relu(h3@lin1_w + b). 16 node-rows staged through LDS per block.
extern "C" __global__ __launch_bounds__(256)
void k_tail(const float* __restrict__ x,
            const float* __restrict__ agg,
            const float* __restrict__ w2c, const float* __restrict__ b2c,
            const float* __restrict__ wi,  const float* __restrict__ bi,
            const float* __restrict__ wl,  const float* __restrict__ bl,
            float* __restrict__ out, int N)
{
    __shared__ float sa[NPB * NF];
    __shared__ float sb[NPB * DIM];
    __shared__ float sc[NPB * DIM];
    int t = threadIdx.x;
    int n0 = blockIdx.x * NPB;

    for (int i = t; i < NPB * NF; i += 256) {
        int n = i >> 6;
        sa[i] = (n0 + n < N) ? agg[(size_t)(n0 + n) * NF + (i & 63)] : 0.0f;
    }
    __syncthreads();

    // stage A: [16,64] @ [64,128] -> ssp -> sb
    #pragma unroll
    for (int p = 0; p < NPB * DIM / 256; p++) {
        int idx = t + p * 256;
        int n = idx >> 7, j = idx & 127;
        float acc = b2c[j];
        #pragma unroll 8
        for (int k = 0; k < NF; k++) acc = fmaf(sa[n * NF + k], w2c[k * DIM + j], acc);
        sb[idx] = ssp_f(acc);
    }
    __syncthreads();

    // stage B: [16,128] @ [128,128] -> sc
    #pragma unroll
    for (int p = 0; p < NPB * DIM / 256; p++) {
        int idx = t + p * 256;
        int n = idx >> 7, j = idx & 127;
        float acc = bi[j];
        #pragma unroll 8
        for (int k = 0; k < DIM; k++) acc = fmaf(sb[n * DIM + k], wi[k * DIM + j], acc);
        sc[idx] = acc;
    }
    __syncthreads();

    // stage C: relu + residual
    #pragma unroll
    for (int p = 0; p < NPB * DIM / 256; p++) {
        int idx = t + p * 256;
        int n = idx >> 7, j = idx & 127;
        if (n0 + n >= N) continue;
        float acc = bl[j];
        #pragma unroll 8
        for (int k = 0; k < DIM; k++) acc = fmaf(sc[n * DIM + k], wl[k * DIM + j], acc);
        float y = fmaxf(acc, 0.0f);
        size_t o = (size_t)(n0 + n) * DIM + j;
        out[o] = x[o] + y;
    }
}

extern "C" void kernel_launch(void* const* d_in, const int* in_sizes, int n_in,
                              void* d_out, int out_size, void* d_ws, size_t ws_size,
                              hipStream_t stream)
{
    const float* x    = (const float*)d_in[0];
    const float* pos  = (const float*)d_in[1];
    const int*   ei   = (const int*)  d_in[2];
    const float* mw1  = (const float*)d_in[3];
    const float* mb1  = (const float*)d_in[4];
    const float* mw2  = (const float*)d_in[5];
    const float* mb2  = (const float*)d_in[6];
    const float* cl1  = (const float*)d_in[7];
    const float* cl2  = (const float*)d_in[8];
    const float* cl2b = (const float*)d_in[9];
    const float* iw   = (const float*)d_in[10];
    const float* ib   = (const float*)d_in[11];
    const float* lw   = (const float*)d_in[12];
    const float* lb   = (const float*)d_in[13];
    float* out = (float*)d_out;

    int N = in_sizes[0] / DIM;
    int E = in_sizes[2] / 2;

    float* h   = (float*)d_ws;
    float* agg = h + (size_t)N * NF;

    hipMemsetAsync(agg, 0, (size_t)N * NF * sizeof(float), stream);

    k_lin1<<<(N * NF + 255) / 256, 256, 0, stream>>>(x, cl1, h, N);
    k_edge<<<(E + 255) / 256, 256, 0, stream>>>(pos, ei, mw1, mb1, mw2, mb2, h, agg, E);
    k_tail<<<(N + NPB - 1) / NPB, 256, 0, stream>>>(x, agg, cl2, cl2b, iw, ib, lw, lb, out, N);
}

// Round 2
// 1319.126 us; speedup vs baseline: 4.6062x; 4.6062x over previous
//
#include <hip/hip_runtime.h>
#include <math.h>

#define NGAUSS 50
#define NF 64
#define DIM 128
#define NPB 16

#define GSTEP (10.0f/49.0f)
#define GCOEFF (-0.5f/(GSTEP*GSTEP))
#define PIC (3.14159265358979323846f/10.0f)
#define LOG2F_ 0.69314718055994530942f

__device__ __forceinline__ float ssp_f(float x){
    // softplus(x) - log(2), numerically stable
    return fmaxf(x, 0.0f) + log1pf(__expf(-fabsf(x))) - LOG2F_;
}

// h = x @ conv_lin1_w   [N,128] @ [128,64] -> [N,64]
extern "C" __global__ __launch_bounds__(256)
void k_lin1(const float* __restrict__ x, const float* __restrict__ w,
            float* __restrict__ h, int N)
{
    int idx = blockIdx.x * 256 + threadIdx.x;
    int n = idx >> 6, j = idx & 63;
    if (n >= N) return;
    const float* xr = x + (size_t)n * DIM;
    float acc = 0.0f;
    #pragma unroll 8
    for (int k = 0; k < DIM; k++) acc = fmaf(xr[k], w[k * NF + j], acc);
    h[(size_t)n * NF + j] = acc;
}

// Edge kernel: wave owns 64 edges (lane = edge) for the MLP, then
// LDS-transposes so the atomic scatter is lane = filter (coalesced 128B
// segments, 1 atomic instruction per edge-half instead of 64 scattered
// dword atomics per edge).
extern "C" __global__ __launch_bounds__(256)
void k_edge(const float* __restrict__ pos,
            const int*   __restrict__ ei,
            const float* __restrict__ w1, const float* __restrict__ b1,
            const float* __restrict__ w2, const float* __restrict__ b2,
            const float* __restrict__ h,
            float* __restrict__ agg, int E)
{
    __shared__ float tile[4][64][33];   // [wave][edge][j-half], pad 33 -> conflict-free
    int lane = threadIdx.x & 63;
    int wid  = threadIdx.x >> 6;
    int cbase = (blockIdx.x * 4 + wid) * 64;
    int e = cbase + lane;
    bool valid = (e < E);
    int s = valid ? ei[e] : 0;
    int d = valid ? ei[E + e] : 0;

    float dx = pos[3*d]   - pos[3*s];
    float dy = pos[3*d+1] - pos[3*s+1];
    float dz = pos[3*d+2] - pos[3*s+2];
    float dist = sqrtf(dx*dx + dy*dy + dz*dz);

    // Gaussian smearing (static array, fully unrolled)
    float ea[NGAUSS];
    #pragma unroll
    for (int m = 0; m < NGAUSS; m++) {
        float t = dist - (float)m * GSTEP;
        ea[m] = __expf(GCOEFF * t * t);
    }

    // out = b2 + ssp(ea@w1 + b1) @ w2, rank-1 updates, all static indexing
    float out[NF];
    #pragma unroll
    for (int j = 0; j < NF; j++) out[j] = b2[j];

    for (int j = 0; j < NF; j++) {            // dynamic, wave-uniform
        float acc = b1[j];
        const float* w1c = w1 + j;            // column j of [50,64]
        #pragma unroll
        for (int m = 0; m < NGAUSS; m++) acc = fmaf(ea[m], w1c[m * NF], acc);
        float hj = ssp_f(acc);
        const float* w2r = w2 + j * NF;       // row j of [64,64]
        #pragma unroll
        for (int j2 = 0; j2 < NF; j2++) out[j2] = fmaf(hj, w2r[j2], out[j2]);
    }

    float Cc = 0.5f * (__cosf(dist * PIC) + 1.0f);
    float scale = valid ? Cc : 0.0f;

    // Transpose + scatter, two j-halves of 32 to bound LDS.
    #pragma unroll
    for (int half = 0; half < 2; half++) {
        __syncthreads();                       // tile reuse guard
        #pragma unroll
        for (int j = 0; j < 32; j++)
            tile[wid][lane][j] = out[half * 32 + j] * scale;
        __syncthreads();

        // 2 edges per iteration: lanes 0..31 -> edge 2*e2, lanes 32..63 -> 2*e2+1
        #pragma unroll 4
        for (int e2 = 0; e2 < 32; e2++) {
            int esel = e2 * 2 + (lane >> 5);
            int s_e = __shfl(s, esel);
            int d_e = __shfl(d, esel);
            int j = half * 32 + (lane & 31);
            float wv = tile[wid][esel][lane & 31];
            float val = wv * h[(size_t)s_e * NF + j];   // coalesced 128B row segment
            atomicAdd(&agg[(size_t)d_e * NF + j], val); // coalesced 128B segment
        }
    }
}

// Fused tail: h2 = ssp(agg@conv_lin2_w + b); h3 = h2@int_lin_w + b;
// out = x + relu(h3@lin1_w + b). 16 node-rows staged through LDS per block.
extern "C" __global__ __launch_bounds__(256)
void k_tail(const float* __restrict__ x,
            const float* __restrict__ agg,
            const float* __restrict__ w2c, const float* __restrict__ b2c,
            const float* __restrict__ wi,  const float* __restrict__ bi,
            const float* __restrict__ wl,  const float* __restrict__ bl,
            float* __restrict__ out, int N)
{
    __shared__ float sa[NPB * NF];
    __shared__ float sb[NPB * DIM];
    __shared__ float sc[NPB * DIM];
    int t = threadIdx.x;
    int n0 = blockIdx.x * NPB;

    for (int i = t; i < NPB * NF; i += 256) {
        int n = i >> 6;
        sa[i] = (n0 + n < N) ? agg[(size_t)(n0 + n) * NF + (i & 63)] : 0.0f;
    }
    __syncthreads();

    #pragma unroll
    for (int p = 0; p < NPB * DIM / 256; p++) {
        int idx = t + p * 256;
        int n = idx >> 7, j = idx & 127;
        float acc = b2c[j];
        #pragma unroll 8
        for (int k = 0; k < NF; k++) acc = fmaf(sa[n * NF + k], w2c[k * DIM + j], acc);
        sb[idx] = ssp_f(acc);
    }
    __syncthreads();

    #pragma unroll
    for (int p = 0; p < NPB * DIM / 256; p++) {
        int idx = t + p * 256;
        int n = idx >> 7, j = idx & 127;
        float acc = bi[j];
        #pragma unroll 8
        for (int k = 0; k < DIM; k++) acc = fmaf(sb[n * DIM + k], wi[k * DIM + j], acc);
        sc[idx] = acc;
    }
    __syncthreads();

    #pragma unroll
    for (int p = 0; p < NPB * DIM / 256; p++) {
        int idx = t + p * 256;
        int n = idx >> 7, j = idx & 127;
        if (n0 + n >= N) continue;
        float acc = bl[j];
        #pragma unroll 8
        for (int k = 0; k < DIM; k++) acc = fmaf(sc[n * DIM + k], wl[k * DIM + j], acc);
        float y = fmaxf(acc, 0.0f);
        size_t o = (size_t)(n0 + n) * DIM + j;
        out[o] = x[o] + y;
    }
}

extern "C" void kernel_launch(void* const* d_in, const int* in_sizes, int n_in,
                              void* d_out, int out_size, void* d_ws, size_t ws_size,
                              hipStream_t stream)
{
    const float* x    = (const float*)d_in[0];
    const float* pos  = (const float*)d_in[1];
    const int*   ei   = (const int*)  d_in[2];
    const float* mw1  = (const float*)d_in[3];
    const float* mb1  = (const float*)d_in[4];
    const float* mw2  = (const float*)d_in[5];
    const float* mb2  = (const float*)d_in[6];
    const float* cl1  = (const float*)d_in[7];
    const float* cl2  = (const float*)d_in[8];
    const float* cl2b = (const float*)d_in[9];
    const float* iw   = (const float*)d_in[10];
    const float* ib   = (const float*)d_in[11];
    const float* lw   = (const float*)d_in[12];
    const float* lb   = (const float*)d_in[13];
    float* out = (float*)d_out;

    int N = in_sizes[0] / DIM;
    int E = in_sizes[2] / 2;

    float* h   = (float*)d_ws;
    float* agg = h + (size_t)N * NF;

    hipMemsetAsync(agg, 0, (size_t)N * NF * sizeof(float), stream);

    k_lin1<<<(N * NF + 255) / 256, 256, 0, stream>>>(x, cl1, h, N);

    int nchunk = (E + 63) / 64;
    k_edge<<<(nchunk + 3) / 4, 256, 0, stream>>>(pos, ei, mw1, mb1, mw2, mb2, h, agg, E);

    k_tail<<<(N + NPB - 1) / NPB, 256, 0, stream>>>(x, agg, cl2, cl2b, iw, ib, lw, lb, out, N);
}

// Round 3
// 575.598 us; speedup vs baseline: 10.5561x; 2.2917x over previous
//
#include <hip/hip_runtime.h>
#include <math.h>

#define NGAUSS 50
#define NF 64
#define DIM 128

#define GSTEP (10.0f/49.0f)
#define GCOEFF (-0.5f/(GSTEP*GSTEP))
#define PIC (3.14159265358979323846f/10.0f)
#define LOG2F_ 0.69314718055994530942f

typedef short v8s __attribute__((ext_vector_type(8)));
typedef float v4f __attribute__((ext_vector_type(4)));
typedef unsigned short ushort_t;

#define MFMA(a,b,c) __builtin_amdgcn_mfma_f32_16x16x32_bf16(a, b, c, 0, 0, 0)

__device__ __forceinline__ unsigned short f2bf(float f) {
    unsigned u = __builtin_bit_cast(unsigned, f);
    unsigned r = (u + 0x7FFFu + ((u >> 16) & 1u)) >> 16;   // RNE
    return (unsigned short)r;
}
__device__ __forceinline__ float bf2f(unsigned short s) {
    return __builtin_bit_cast(float, ((unsigned)s) << 16);
}
__device__ __forceinline__ float ssp_f(float x) {
    // softplus(x) - log2, cheap transcendental form (v_exp + v_log)
    return fmaxf(x, 0.0f) + __logf(1.0f + __expf(-fabsf(x))) - LOG2F_;
}

// ---------- prep: weights -> bf16, transposed to [col][k] ----------
extern "C" __global__ __launch_bounds__(256)
void k_prep(const float* __restrict__ w1, const float* __restrict__ w2,
            const float* __restrict__ cl1, const float* __restrict__ w2c,
            const float* __restrict__ wi, const float* __restrict__ wl,
            ushort_t* __restrict__ w1T, ushort_t* __restrict__ w2T,
            ushort_t* __restrict__ cl1T, ushort_t* __restrict__ w2cT,
            ushort_t* __restrict__ wiT, ushort_t* __restrict__ wlT)
{
    int id = blockIdx.x * 256 + threadIdx.x;
    int stride = gridDim.x * 256;
    for (int i = id; i < 64*64;   i += stride){ int c=i>>6, k=i&63;  w1T[i]  = f2bf(k < NGAUSS ? w1[k*64+c] : 0.0f); }
    for (int i = id; i < 64*64;   i += stride){ int c=i>>6, k=i&63;  w2T[i]  = f2bf(w2[k*64+c]); }
    for (int i = id; i < 64*128;  i += stride){ int c=i>>7, k=i&127; cl1T[i] = f2bf(cl1[k*64+c]); }
    for (int i = id; i < 128*64;  i += stride){ int c=i>>6, k=i&63;  w2cT[i] = f2bf(w2c[k*128+c]); }
    for (int i = id; i < 128*128; i += stride){ int c=i>>7, k=i&127; wiT[i]  = f2bf(wi[k*128+c]); }
    for (int i = id; i < 128*128; i += stride){ int c=i>>7, k=i&127; wlT[i]  = f2bf(wl[k*128+c]); }
}

// ---------- h = x @ conv_lin1_w -> bf16, MFMA, wave = 32 rows ----------
extern "C" __global__ __launch_bounds__(256)
void k_lin1_mfma(const float* __restrict__ x, const ushort_t* __restrict__ cl1T,
                 ushort_t* __restrict__ h_bf, int N)
{
    int l = threadIdx.x & 63, w = threadIdx.x >> 6;
    int base = (blockIdx.x * 4 + w) * 32;
    int colb = l & 15, krow = (l >> 4) * 8;

    v4f C[2][4];
    #pragma unroll
    for (int m = 0; m < 2; m++)
        #pragma unroll
        for (int n = 0; n < 4; n++) C[m][n] = (v4f){0,0,0,0};

    #pragma unroll
    for (int kt = 0; kt < 4; kt++) {
        v8s am[2];
        #pragma unroll
        for (int m = 0; m < 2; m++) {
            int row = base + m*16 + colb;
            v8s a = (v8s){0,0,0,0,0,0,0,0};
            if (row < N) {
                const float4* p = (const float4*)(x + (size_t)row*DIM + kt*32 + krow);
                float4 f0 = p[0], f1 = p[1];
                a[0]=(short)f2bf(f0.x); a[1]=(short)f2bf(f0.y); a[2]=(short)f2bf(f0.z); a[3]=(short)f2bf(f0.w);
                a[4]=(short)f2bf(f1.x); a[5]=(short)f2bf(f1.y); a[6]=(short)f2bf(f1.z); a[7]=(short)f2bf(f1.w);
            }
            am[m] = a;
        }
        #pragma unroll
        for (int n = 0; n < 4; n++) {
            v8s b = *(const v8s*)(cl1T + (n*16 + colb)*DIM + kt*32 + krow);
            #pragma unroll
            for (int m = 0; m < 2; m++) C[m][n] = MFMA(am[m], b, C[m][n]);
        }
    }
    #pragma unroll
    for (int m = 0; m < 2; m++)
        #pragma unroll
        for (int n = 0; n < 4; n++)
            #pragma unroll
            for (int i = 0; i < 4; i++) {
                int row = base + m*16 + (l>>4)*4 + i;
                if (row < N) h_bf[(size_t)row*NF + n*16 + colb] = f2bf(C[m][n][i]);
            }
}

// ---------- edge kernel: MFMA MLP + LDS-transposed coalesced scatter ----------
extern "C" __global__ __launch_bounds__(256)
void k_edge_mfma(const float* __restrict__ pos, const int* __restrict__ ei,
                 const ushort_t* __restrict__ h_bf,
                 const ushort_t* __restrict__ w1T, const ushort_t* __restrict__ w2T,
                 const float* __restrict__ b1, const float* __restrict__ b2,
                 float* __restrict__ agg, int E)
{
    __shared__ __align__(16) char lds[4][64*128];   // per-wave 64x64 bf16, XOR-swizzled
    int l = threadIdx.x & 63, w = threadIdx.x >> 6;
    char* T = lds[w];
    size_t ebase = ((size_t)blockIdx.x * 4 + w) * 64;
    int e = (int)(ebase + l);
    bool valid = e < E;
    int s = valid ? ei[e] : 0;
    int d = valid ? ei[E + e] : 0;

    float dx = pos[3*d]   - pos[3*s];
    float dy = pos[3*d+1] - pos[3*s+1];
    float dz = pos[3*d+2] - pos[3*s+2];
    float dist = sqrtf(dx*dx + dy*dy + dz*dz);
    float Cc = valid ? 0.5f * (__cosf(dist * PIC) + 1.0f) : 0.0f;

    int colb = l & 15, krow = (l >> 4) * 8;

    // persistent B-fragments + biases
    v8s B1[2][4], B2[2][4];
    float b1v[4], b2v[4];
    #pragma unroll
    for (int n = 0; n < 4; n++) {
        b1v[n] = b1[n*16 + colb];
        b2v[n] = b2[n*16 + colb];
        #pragma unroll
        for (int kt = 0; kt < 2; kt++) {
            B1[kt][n] = *(const v8s*)(w1T + (n*16 + colb)*64 + kt*32 + krow);
            B2[kt][n] = *(const v8s*)(w2T + (n*16 + colb)*64 + kt*32 + krow);
        }
    }

    // layer 1: ea (computed directly in A-frag layout) @ w1
    v4f C1[4][4];
    #pragma unroll
    for (int m = 0; m < 4; m++)
        #pragma unroll
        for (int n = 0; n < 4; n++) C1[m][n] = (v4f){0,0,0,0};

    #pragma unroll
    for (int m = 0; m < 4; m++) {
        float dm = __shfl(dist, m*16 + colb);
        #pragma unroll
        for (int kt = 0; kt < 2; kt++) {
            v8s a;
            #pragma unroll
            for (int i = 0; i < 8; i++) {
                float off = (float)(kt*32 + krow + i) * GSTEP;
                float t = dm - off;
                a[i] = (short)f2bf(__expf(GCOEFF * t * t));
            }
            #pragma unroll
            for (int n = 0; n < 4; n++) C1[m][n] = MFMA(a, B1[kt][n], C1[m][n]);
        }
    }

    // ssp -> bf16 -> swizzled LDS tile (row=edge, col=j1)
    #pragma unroll
    for (int m = 0; m < 4; m++)
        #pragma unroll
        for (int n = 0; n < 4; n++)
            #pragma unroll
            for (int i = 0; i < 4; i++) {
                int row = m*16 + (l>>4)*4 + i;
                int col = n*16 + colb;
                float v = ssp_f(C1[m][n][i] + b1v[n]);
                *(ushort_t*)(T + row*128 + ((col*2) ^ ((row&7)<<4))) = f2bf(v);
            }
    __syncthreads();

    // layer 2: hid @ w2
    v4f C2[4][4];
    #pragma unroll
    for (int m = 0; m < 4; m++)
        #pragma unroll
        for (int n = 0; n < 4; n++) C2[m][n] = (v4f){0,0,0,0};

    #pragma unroll
    for (int m = 0; m < 4; m++) {
        int row = m*16 + colb;
        #pragma unroll
        for (int kt = 0; kt < 2; kt++) {
            v8s a = *(const v8s*)(T + row*128 + ((kt*64 + krow*2) ^ ((row&7)<<4)));
            #pragma unroll
            for (int n = 0; n < 4; n++) C2[m][n] = MFMA(a, B2[kt][n], C2[m][n]);
        }
    }
    __syncthreads();   // all layer-2 reads done before overwrite

    // W*Cc -> bf16 -> same tile
    #pragma unroll
    for (int m = 0; m < 4; m++)
        #pragma unroll
        for (int i = 0; i < 4; i++) {
            int row = m*16 + (l>>4)*4 + i;
            float cc = __shfl(Cc, row);
            #pragma unroll
            for (int n = 0; n < 4; n++) {
                int col = n*16 + colb;
                float wv = (C2[m][n][i] + b2v[n]) * cc;
                *(ushort_t*)(T + row*128 + ((col*2) ^ ((row&7)<<4))) = f2bf(wv);
            }
        }
    __syncthreads();

    // scatter: lane = filter, one edge per iteration, coalesced 256B atomics
    #pragma unroll 16
    for (int e2 = 0; e2 < 64; e2++) {
        int se = __shfl(s, e2);
        int de = __shfl(d, e2);
        float wv = bf2f(*(const ushort_t*)(T + e2*128 + ((l*2) ^ ((e2&7)<<4))));
        float hv = bf2f(h_bf[(size_t)se*NF + l]);
        atomicAdd(agg + (size_t)de*NF + l, wv * hv);
    }
}

// ---------- fused tail, MFMA, wave = 32 rows ----------
extern "C" __global__ __launch_bounds__(256)
void k_tail_mfma(const float* __restrict__ x, const float* __restrict__ agg,
                 const ushort_t* __restrict__ w2cT, const float* __restrict__ b2c,
                 const ushort_t* __restrict__ wiT,  const float* __restrict__ bi,
                 const ushort_t* __restrict__ wlT,  const float* __restrict__ bl,
                 float* __restrict__ out, int N)
{
    __shared__ __align__(16) char lds[4][32*256];   // per-wave 32x128 bf16, XOR-swizzled
    int l = threadIdx.x & 63, w = threadIdx.x >> 6;
    char* T = lds[w];
    int base = (blockIdx.x * 4 + w) * 32;
    int colb = l & 15, krow = (l >> 4) * 8;

    float b2cv[8], biv[8], blv[8];
    #pragma unroll
    for (int n = 0; n < 8; n++) {
        b2cv[n] = b2c[n*16 + colb];
        biv[n]  = bi[n*16 + colb];
        blv[n]  = bl[n*16 + colb];
    }

    // stage A: agg[32,64] @ w2cT -> ssp -> LDS
    v4f C[2][8];
    #pragma unroll
    for (int m = 0; m < 2; m++)
        #pragma unroll
        for (int n = 0; n < 8; n++) C[m][n] = (v4f){0,0,0,0};

    #pragma unroll
    for (int kt = 0; kt < 2; kt++) {
        v8s am[2];
        #pragma unroll
        for (int m = 0; m < 2; m++) {
            int row = base + m*16 + colb;
            v8s a = (v8s){0,0,0,0,0,0,0,0};
            if (row < N) {
                const float4* p = (const float4*)(agg + (size_t)row*NF + kt*32 + krow);
                float4 f0 = p[0], f1 = p[1];
                a[0]=(short)f2bf(f0.x); a[1]=(short)f2bf(f0.y); a[2]=(short)f2bf(f0.z); a[3]=(short)f2bf(f0.w);
                a[4]=(short)f2bf(f1.x); a[5]=(short)f2bf(f1.y); a[6]=(short)f2bf(f1.z); a[7]=(short)f2bf(f1.w);
            }
            am[m] = a;
        }
        #pragma unroll
        for (int n = 0; n < 8; n++) {
            v8s b = *(const v8s*)(w2cT + (n*16 + colb)*64 + kt*32 + krow);
            #pragma unroll
            for (int m = 0; m < 2; m++) C[m][n] = MFMA(am[m], b, C[m][n]);
        }
    }
    #pragma unroll
    for (int m = 0; m < 2; m++)
        #pragma unroll
        for (int n = 0; n < 8; n++)
            #pragma unroll
            for (int i = 0; i < 4; i++) {
                int rl = m*16 + (l>>4)*4 + i;
                int col = n*16 + colb;
                float v = ssp_f(C[m][n][i] + b2cv[n]);
                *(ushort_t*)(T + rl*256 + ((col*2) ^ ((rl&7)<<4))) = f2bf(v);
            }
    __syncthreads();

    // stage B: h2[32,128] @ wiT
    v4f D[2][8];
    #pragma unroll
    for (int m = 0; m < 2; m++)
        #pragma unroll
        for (int n = 0; n < 8; n++) D[m][n] = (v4f){0,0,0,0};

    v8s af[2][4];
    #pragma unroll
    for (int m = 0; m < 2; m++)
        #pragma unroll
        for (int kt = 0; kt < 4; kt++) {
            int rl = m*16 + colb;
            af[m][kt] = *(const v8s*)(T + rl*256 + ((kt*64 + krow*2) ^ ((rl&7)<<4)));
        }
    #pragma unroll
    for (int kt = 0; kt < 4; kt++)
        #pragma unroll
        for (int n = 0; n < 8; n++) {
            v8s b = *(const v8s*)(wiT + (n*16 + colb)*DIM + kt*32 + krow);
            #pragma unroll
            for (int m = 0; m < 2; m++) D[m][n] = MFMA(af[m][kt], b, D[m][n]);
        }
    __syncthreads();
    #pragma unroll
    for (int m = 0; m < 2; m++)
        #pragma unroll
        for (int n = 0; n < 8; n++)
            #pragma unroll
            for (int i = 0; i < 4; i++) {
                int rl = m*16 + (l>>4)*4 + i;
                int col = n*16 + colb;
                *(ushort_t*)(T + rl*256 + ((col*2) ^ ((rl&7)<<4))) = f2bf(D[m][n][i] + biv[n]);
            }
    __syncthreads();

    // stage C: h3[32,128] @ wlT -> relu -> +x -> out
    v4f G[2][8];
    #pragma unroll
    for (int m = 0; m < 2; m++)
        #pragma unroll
        for (int n = 0; n < 8; n++) G[m][n] = (v4f){0,0,0,0};

    #pragma unroll
    for (int m = 0; m < 2; m++)
        #pragma unroll
        for (int kt = 0; kt < 4; kt++) {
            int rl = m*16 + colb;
            af[m][kt] = *(const v8s*)(T + rl*256 + ((kt*64 + krow*2) ^ ((rl&7)<<4)));
        }
    #pragma unroll
    for (int kt = 0; kt < 4; kt++)
        #pragma unroll
        for (int n = 0; n < 8; n++) {
            v8s b = *(const v8s*)(wlT + (n*16 + colb)*DIM + kt*32 + krow);
            #pragma unroll
            for (int m = 0; m < 2; m++) G[m][n] = MFMA(af[m][kt], b, G[m][n]);
        }

    #pragma unroll
    for (int m = 0; m < 2; m++)
        #pragma unroll
        for (int n = 0; n < 8; n++)
            #pragma unroll
            for (int i = 0; i < 4; i++) {
                int row = base + m*16 + (l>>4)*4 + i;
                if (row < N) {
                    int col = n*16 + colb;
                    size_t o = (size_t)row*DIM + col;
                    out[o] = x[o] + fmaxf(G[m][n][i] + blv[n], 0.0f);
                }
            }
}

extern "C" void kernel_launch(void* const* d_in, const int* in_sizes, int n_in,
                              void* d_out, int out_size, void* d_ws, size_t ws_size,
                              hipStream_t stream)
{
    const float* x    = (const float*)d_in[0];
    const float* pos  = (const float*)d_in[1];
    const int*   ei   = (const int*)  d_in[2];
    const float* mw1  = (const float*)d_in[3];
    const float* mb1  = (const float*)d_in[4];
    const float* mw2  = (const float*)d_in[5];
    const float* mb2  = (const float*)d_in[6];
    const float* cl1  = (const float*)d_in[7];
    const float* cl2  = (const float*)d_in[8];
    const float* cl2b = (const float*)d_in[9];
    const float* iw   = (const float*)d_in[10];
    const float* ib   = (const float*)d_in[11];
    const float* lw   = (const float*)d_in[12];
    const float* lb   = (const float*)d_in[13];
    float* out = (float*)d_out;

    int N = in_sizes[0] / DIM;
    int E = in_sizes[2] / 2;

    char* W = (char*)d_ws;
    size_t h_bytes   = (size_t)N * NF * sizeof(ushort_t);
    size_t agg_bytes = (size_t)N * NF * sizeof(float);
    ushort_t* h_bf = (ushort_t*)W;
    float*    agg  = (float*)(W + h_bytes);
    ushort_t* wT   = (ushort_t*)(W + h_bytes + agg_bytes);
    ushort_t* w1T  = wT;
    ushort_t* w2T  = wT + 4096;
    ushort_t* cl1T = wT + 8192;
    ushort_t* w2cT = wT + 16384;
    ushort_t* wiT  = wT + 24576;
    ushort_t* wlT  = wT + 40960;

    hipMemsetAsync(agg, 0, agg_bytes, stream);

    k_prep<<<60, 256, 0, stream>>>(mw1, mw2, cl1, cl2, iw, lw,
                                   w1T, w2T, cl1T, w2cT, wiT, wlT);

    k_lin1_mfma<<<(N + 127) / 128, 256, 0, stream>>>(x, cl1T, h_bf, N);

    int ewaves = (E + 63) / 64;
    k_edge_mfma<<<(ewaves + 3) / 4, 256, 0, stream>>>(pos, ei, h_bf, w1T, w2T,
                                                      mb1, mb2, agg, E);

    k_tail_mfma<<<(N + 127) / 128, 256, 0, stream>>>(x, agg, w2cT, cl2b,
                                                     wiT, ib, wlT, lb, out, N);
}

// Round 4
// 571.275 us; speedup vs baseline: 10.6360x; 1.0076x over previous
//
#include <hip/hip_runtime.h>
#include <math.h>

#define NGAUSS 50
#define NF 64
#define DIM 128

#define GSTEP (10.0f/49.0f)
#define GCOEFF (-0.5f/(GSTEP*GSTEP))
#define PIC (3.14159265358979323846f/10.0f)
#define LOG2F_ 0.69314718055994530942f

typedef short v8s __attribute__((ext_vector_type(8)));
typedef float v4f __attribute__((ext_vector_type(4)));
typedef unsigned short ushort_t;

#define MFMA(a,b,c) __builtin_amdgcn_mfma_f32_16x16x32_bf16(a, b, c, 0, 0, 0)
#define WAVE_BAR() __builtin_amdgcn_wave_barrier()

__device__ __forceinline__ unsigned short f2bf(float f) {
    unsigned u = __builtin_bit_cast(unsigned, f);
    unsigned r = (u + 0x7FFFu + ((u >> 16) & 1u)) >> 16;   // RNE
    return (unsigned short)r;
}
__device__ __forceinline__ float bf2f(unsigned short s) {
    return __builtin_bit_cast(float, ((unsigned)s) << 16);
}
__device__ __forceinline__ float ssp_f(float x) {
    return fmaxf(x, 0.0f) + __logf(1.0f + __expf(-fabsf(x))) - LOG2F_;
}

// ---------- prep: weights -> bf16, transposed to [col][k] ----------
extern "C" __global__ __launch_bounds__(256)
void k_prep(const float* __restrict__ w1, const float* __restrict__ w2,
            const float* __restrict__ cl1, const float* __restrict__ w2c,
            const float* __restrict__ wi, const float* __restrict__ wl,
            ushort_t* __restrict__ w1T, ushort_t* __restrict__ w2T,
            ushort_t* __restrict__ cl1T, ushort_t* __restrict__ w2cT,
            ushort_t* __restrict__ wiT, ushort_t* __restrict__ wlT)
{
    int id = blockIdx.x * 256 + threadIdx.x;
    int stride = gridDim.x * 256;
    for (int i = id; i < 64*64;   i += stride){ int c=i>>6, k=i&63;  w1T[i]  = f2bf(k < NGAUSS ? w1[k*64+c] : 0.0f); }
    for (int i = id; i < 64*64;   i += stride){ int c=i>>6, k=i&63;  w2T[i]  = f2bf(w2[k*64+c]); }
    for (int i = id; i < 64*128;  i += stride){ int c=i>>7, k=i&127; cl1T[i] = f2bf(cl1[k*64+c]); }
    for (int i = id; i < 128*64;  i += stride){ int c=i>>6, k=i&63;  w2cT[i] = f2bf(w2c[k*128+c]); }
    for (int i = id; i < 128*128; i += stride){ int c=i>>7, k=i&127; wiT[i]  = f2bf(wi[k*128+c]); }
    for (int i = id; i < 128*128; i += stride){ int c=i>>7, k=i&127; wlT[i]  = f2bf(wl[k*128+c]); }
}

// ---------- h = x @ conv_lin1_w -> bf16, MFMA, wave = 32 rows ----------
// Also zeroes agg for this block's rows (replaces memset dispatch).
extern "C" __global__ __launch_bounds__(256)
void k_lin1_mfma(const float* __restrict__ x, const ushort_t* __restrict__ cl1T,
                 ushort_t* __restrict__ h_bf, float* __restrict__ agg, int N)
{
    // zero agg rows [blockIdx.x*128, +128): 128*64 floats = 2048 float4
    {
        int nb = blockIdx.x * 128;
        int rows = min(128, N - nb);
        if (rows > 0) {
            float4* ap = (float4*)(agg + (size_t)nb * NF);
            int tot = rows * (NF / 4);
            for (int i = threadIdx.x; i < tot; i += 256)
                ap[i] = (float4){0,0,0,0};
        }
    }

    int l = threadIdx.x & 63, w = threadIdx.x >> 6;
    int base = (blockIdx.x * 4 + w) * 32;
    int colb = l & 15, krow = (l >> 4) * 8;

    v4f C[2][4];
    #pragma unroll
    for (int m = 0; m < 2; m++)
        #pragma unroll
        for (int n = 0; n < 4; n++) C[m][n] = (v4f){0,0,0,0};

    #pragma unroll
    for (int kt = 0; kt < 4; kt++) {
        v8s am[2];
        #pragma unroll
        for (int m = 0; m < 2; m++) {
            int row = base + m*16 + colb;
            v8s a = (v8s){0,0,0,0,0,0,0,0};
            if (row < N) {
                const float4* p = (const float4*)(x + (size_t)row*DIM + kt*32 + krow);
                float4 f0 = p[0], f1 = p[1];
                a[0]=(short)f2bf(f0.x); a[1]=(short)f2bf(f0.y); a[2]=(short)f2bf(f0.z); a[3]=(short)f2bf(f0.w);
                a[4]=(short)f2bf(f1.x); a[5]=(short)f2bf(f1.y); a[6]=(short)f2bf(f1.z); a[7]=(short)f2bf(f1.w);
            }
            am[m] = a;
        }
        #pragma unroll
        for (int n = 0; n < 4; n++) {
            v8s b = *(const v8s*)(cl1T + (n*16 + colb)*DIM + kt*32 + krow);
            #pragma unroll
            for (int m = 0; m < 2; m++) C[m][n] = MFMA(am[m], b, C[m][n]);
        }
    }
    #pragma unroll
    for (int m = 0; m < 2; m++)
        #pragma unroll
        for (int n = 0; n < 4; n++)
            #pragma unroll
            for (int i = 0; i < 4; i++) {
                int row = base + m*16 + (l>>4)*4 + i;
                if (row < N) h_bf[(size_t)row*NF + n*16 + colb] = f2bf(C[m][n][i]);
            }
}

// ---------- edge kernel: MFMA MLP + coalesced scatter ----------
// No block barriers: each wave owns its LDS tile; waves free-run so one
// wave's scatter (memory latency) overlaps another's MFMA phase.
extern "C" __global__ __launch_bounds__(256)
void k_edge_mfma(const float* __restrict__ pos, const int* __restrict__ ei,
                 const ushort_t* __restrict__ h_bf,
                 const ushort_t* __restrict__ w1T, const ushort_t* __restrict__ w2T,
                 const float* __restrict__ b1, const float* __restrict__ b2,
                 float* __restrict__ agg, int E)
{
    __shared__ __align__(16) char lds[4][64*128];   // per-wave 64x64 bf16, XOR-swizzled
    int l = threadIdx.x & 63, w = threadIdx.x >> 6;
    char* T = lds[w];
    size_t ebase = ((size_t)blockIdx.x * 4 + w) * 64;
    int e = (int)(ebase + l);
    bool valid = e < E;
    int s = valid ? ei[e] : 0;
    int d = valid ? ei[E + e] : 0;

    float dx = pos[3*d]   - pos[3*s];
    float dy = pos[3*d+1] - pos[3*s+1];
    float dz = pos[3*d+2] - pos[3*s+2];
    float dist = sqrtf(dx*dx + dy*dy + dz*dz);
    float Cc = valid ? 0.5f * (__cosf(dist * PIC) + 1.0f) : 0.0f;
    int cci = __builtin_bit_cast(int, Cc);

    int colb = l & 15, krow = (l >> 4) * 8;

    float b1v[4], b2v[4];
    #pragma unroll
    for (int n = 0; n < 4; n++) { b1v[n] = b1[n*16 + colb]; b2v[n] = b2[n*16 + colb]; }

    // layer 1: ea (computed directly in A-frag layout) @ w1
    v4f C1[4][4];
    #pragma unroll
    for (int m = 0; m < 4; m++)
        #pragma unroll
        for (int n = 0; n < 4; n++) C1[m][n] = (v4f){0,0,0,0};
    {
        v8s B1[2][4];
        #pragma unroll
        for (int n = 0; n < 4; n++)
            #pragma unroll
            for (int kt = 0; kt < 2; kt++)
                B1[kt][n] = *(const v8s*)(w1T + (n*16 + colb)*64 + kt*32 + krow);

        #pragma unroll
        for (int m = 0; m < 4; m++) {
            float dm = __shfl(dist, m*16 + colb);
            #pragma unroll
            for (int kt = 0; kt < 2; kt++) {
                v8s a;
                #pragma unroll
                for (int i = 0; i < 8; i++) {
                    float off = (float)(kt*32 + krow + i) * GSTEP;
                    float t = dm - off;
                    a[i] = (short)f2bf(__expf(GCOEFF * t * t));
                }
                #pragma unroll
                for (int n = 0; n < 4; n++) C1[m][n] = MFMA(a, B1[kt][n], C1[m][n]);
            }
        }
    }

    // ssp -> bf16 -> swizzled LDS tile (row=edge, col=j1)
    #pragma unroll
    for (int m = 0; m < 4; m++)
        #pragma unroll
        for (int n = 0; n < 4; n++)
            #pragma unroll
            for (int i = 0; i < 4; i++) {
                int row = m*16 + (l>>4)*4 + i;
                int col = n*16 + colb;
                float v = ssp_f(C1[m][n][i] + b1v[n]);
                *(ushort_t*)(T + row*128 + ((col*2) ^ ((row&7)<<4))) = f2bf(v);
            }
    WAVE_BAR();

    // layer 2: hid @ w2 (DS ops are in-order per wave; compiler inserts lgkmcnt)
    v4f C2[4][4];
    #pragma unroll
    for (int m = 0; m < 4; m++)
        #pragma unroll
        for (int n = 0; n < 4; n++) C2[m][n] = (v4f){0,0,0,0};
    {
        v8s B2[2][4];
        #pragma unroll
        for (int n = 0; n < 4; n++)
            #pragma unroll
            for (int kt = 0; kt < 2; kt++)
                B2[kt][n] = *(const v8s*)(w2T + (n*16 + colb)*64 + kt*32 + krow);

        #pragma unroll
        for (int m = 0; m < 4; m++) {
            int row = m*16 + colb;
            #pragma unroll
            for (int kt = 0; kt < 2; kt++) {
                v8s a = *(const v8s*)(T + row*128 + ((kt*64 + krow*2) ^ ((row&7)<<4)));
                #pragma unroll
                for (int n = 0; n < 4; n++) C2[m][n] = MFMA(a, B2[kt][n], C2[m][n]);
            }
        }
    }
    WAVE_BAR();   // all layer-2 reads precede the W overwrite below (WAR)

    // W = C2 + b2 -> bf16 -> same tile (Cc folded into scatter)
    #pragma unroll
    for (int m = 0; m < 4; m++)
        #pragma unroll
        for (int n = 0; n < 4; n++)
            #pragma unroll
            for (int i = 0; i < 4; i++) {
                int row = m*16 + (l>>4)*4 + i;
                int col = n*16 + colb;
                *(ushort_t*)(T + row*128 + ((col*2) ^ ((row&7)<<4))) = f2bf(C2[m][n][i] + b2v[n]);
            }
    WAVE_BAR();

    // scatter: lane = filter, fully unrolled; readlane (literal) -> scalar
    // base addresses for gather + atomic, coalesced 256B segments.
    #pragma unroll
    for (int e2 = 0; e2 < 64; e2++) {
        int se = __builtin_amdgcn_readlane(s, e2);
        int de = __builtin_amdgcn_readlane(d, e2);
        float cce = __builtin_bit_cast(float, __builtin_amdgcn_readlane(cci, e2));
        float wv = bf2f(*(const ushort_t*)(T + e2*128 + ((l*2) ^ ((e2&7)<<4))));
        float hv = bf2f(h_bf[(size_t)se*NF + l]);
        atomicAdd(agg + (size_t)de*NF + l, wv * cce * hv);
    }
}

// ---------- fused tail, MFMA, wave = 32 rows, no block barriers ----------
extern "C" __global__ __launch_bounds__(256)
void k_tail_mfma(const float* __restrict__ x, const float* __restrict__ agg,
                 const ushort_t* __restrict__ w2cT, const float* __restrict__ b2c,
                 const ushort_t* __restrict__ wiT,  const float* __restrict__ bi,
                 const ushort_t* __restrict__ wlT,  const float* __restrict__ bl,
                 float* __restrict__ out, int N)
{
    __shared__ __align__(16) char lds[4][32*256];   // per-wave 32x128 bf16, XOR-swizzled
    int l = threadIdx.x & 63, w = threadIdx.x >> 6;
    char* T = lds[w];
    int base = (blockIdx.x * 4 + w) * 32;
    int colb = l & 15, krow = (l >> 4) * 8;

    float b2cv[8], biv[8], blv[8];
    #pragma unroll
    for (int n = 0; n < 8; n++) {
        b2cv[n] = b2c[n*16 + colb];
        biv[n]  = bi[n*16 + colb];
        blv[n]  = bl[n*16 + colb];
    }

    // stage A: agg[32,64] @ w2cT -> ssp -> LDS
    v4f C[2][8];
    #pragma unroll
    for (int m = 0; m < 2; m++)
        #pragma unroll
        for (int n = 0; n < 8; n++) C[m][n] = (v4f){0,0,0,0};

    #pragma unroll
    for (int kt = 0; kt < 2; kt++) {
        v8s am[2];
        #pragma unroll
        for (int m = 0; m < 2; m++) {
            int row = base + m*16 + colb;
            v8s a = (v8s){0,0,0,0,0,0,0,0};
            if (row < N) {
                const float4* p = (const float4*)(agg + (size_t)row*NF + kt*32 + krow);
                float4 f0 = p[0], f1 = p[1];
                a[0]=(short)f2bf(f0.x); a[1]=(short)f2bf(f0.y); a[2]=(short)f2bf(f0.z); a[3]=(short)f2bf(f0.w);
                a[4]=(short)f2bf(f1.x); a[5]=(short)f2bf(f1.y); a[6]=(short)f2bf(f1.z); a[7]=(short)f2bf(f1.w);
            }
            am[m] = a;
        }
        #pragma unroll
        for (int n = 0; n < 8; n++) {
            v8s b = *(const v8s*)(w2cT + (n*16 + colb)*64 + kt*32 + krow);
            #pragma unroll
            for (int m = 0; m < 2; m++) C[m][n] = MFMA(am[m], b, C[m][n]);
        }
    }
    #pragma unroll
    for (int m = 0; m < 2; m++)
        #pragma unroll
        for (int n = 0; n < 8; n++)
            #pragma unroll
            for (int i = 0; i < 4; i++) {
                int rl = m*16 + (l>>4)*4 + i;
                int col = n*16 + colb;
                float v = ssp_f(C[m][n][i] + b2cv[n]);
                *(ushort_t*)(T + rl*256 + ((col*2) ^ ((rl&7)<<4))) = f2bf(v);
            }
    WAVE_BAR();

    // stage B: h2[32,128] @ wiT
    v4f D[2][8];
    #pragma unroll
    for (int m = 0; m < 2; m++)
        #pragma unroll
        for (int n = 0; n < 8; n++) D[m][n] = (v4f){0,0,0,0};

    v8s af[2][4];
    #pragma unroll
    for (int m = 0; m < 2; m++)
        #pragma unroll
        for (int kt = 0; kt < 4; kt++) {
            int rl = m*16 + colb;
            af[m][kt] = *(const v8s*)(T + rl*256 + ((kt*64 + krow*2) ^ ((rl&7)<<4)));
        }
    #pragma unroll
    for (int kt = 0; kt < 4; kt++)
        #pragma unroll
        for (int n = 0; n < 8; n++) {
            v8s b = *(const v8s*)(wiT + (n*16 + colb)*DIM + kt*32 + krow);
            #pragma unroll
            for (int m = 0; m < 2; m++) D[m][n] = MFMA(af[m][kt], b, D[m][n]);
        }
    WAVE_BAR();
    #pragma unroll
    for (int m = 0; m < 2; m++)
        #pragma unroll
        for (int n = 0; n < 8; n++)
            #pragma unroll
            for (int i = 0; i < 4; i++) {
                int rl = m*16 + (l>>4)*4 + i;
                int col = n*16 + colb;
                *(ushort_t*)(T + rl*256 + ((col*2) ^ ((rl&7)<<4))) = f2bf(D[m][n][i] + biv[n]);
            }
    WAVE_BAR();

    // stage C: h3[32,128] @ wlT -> relu -> +x -> out
    v4f G[2][8];
    #pragma unroll
    for (int m = 0; m < 2; m++)
        #pragma unroll
        for (int n = 0; n < 8; n++) G[m][n] = (v4f){0,0,0,0};

    #pragma unroll
    for (int m = 0; m < 2; m++)
        #pragma unroll
        for (int kt = 0; kt < 4; kt++) {
            int rl = m*16 + colb;
            af[m][kt] = *(const v8s*)(T + rl*256 + ((kt*64 + krow*2) ^ ((rl&7)<<4)));
        }
    #pragma unroll
    for (int kt = 0; kt < 4; kt++)
        #pragma unroll
        for (int n = 0; n < 8; n++) {
            v8s b = *(const v8s*)(wlT + (n*16 + colb)*DIM + kt*32 + krow);
            #pragma unroll
            for (int m = 0; m < 2; m++) G[m][n] = MFMA(af[m][kt], b, G[m][n]);
        }

    #pragma unroll
    for (int m = 0; m < 2; m++)
        #pragma unroll
        for (int n = 0; n < 8; n++)
            #pragma unroll
            for (int i = 0; i < 4; i++) {
                int row = base + m*16 + (l>>4)*4 + i;
                if (row < N) {
                    int col = n*16 + colb;
                    size_t o = (size_t)row*DIM + col;
                    out[o] = x[o] + fmaxf(G[m][n][i] + blv[n], 0.0f);
                }
            }
}

extern "C" void kernel_launch(void* const* d_in, const int* in_sizes, int n_in,
                              void* d_out, int out_size, void* d_ws, size_t ws_size,
                              hipStream_t stream)
{
    const float* x    = (const float*)d_in[0];
    const float* pos  = (const float*)d_in[1];
    const int*   ei   = (const int*)  d_in[2];
    const float* mw1  = (const float*)d_in[3];
    const float* mb1  = (const float*)d_in[4];
    const float* mw2  = (const float*)d_in[5];
    const float* mb2  = (const float*)d_in[6];
    const float* cl1  = (const float*)d_in[7];
    const float* cl2  = (const float*)d_in[8];
    const float* cl2b = (const float*)d_in[9];
    const float* iw   = (const float*)d_in[10];
    const float* ib   = (const float*)d_in[11];
    const float* lw   = (const float*)d_in[12];
    const float* lb   = (const float*)d_in[13];
    float* out = (float*)d_out;

    int N = in_sizes[0] / DIM;
    int E = in_sizes[2] / 2;

    char* W = (char*)d_ws;
    size_t h_bytes   = (size_t)N * NF * sizeof(ushort_t);
    size_t agg_bytes = (size_t)N * NF * sizeof(float);
    ushort_t* h_bf = (ushort_t*)W;
    float*    agg  = (float*)(W + h_bytes);
    ushort_t* wT   = (ushort_t*)(W + h_bytes + agg_bytes);
    ushort_t* w1T  = wT;
    ushort_t* w2T  = wT + 4096;
    ushort_t* cl1T = wT + 8192;
    ushort_t* w2cT = wT + 16384;
    ushort_t* wiT  = wT + 24576;
    ushort_t* wlT  = wT + 40960;

    k_prep<<<60, 256, 0, stream>>>(mw1, mw2, cl1, cl2, iw, lw,
                                   w1T, w2T, cl1T, w2cT, wiT, wlT);

    k_lin1_mfma<<<(N + 127) / 128, 256, 0, stream>>>(x, cl1T, h_bf, agg, N);

    int ewaves = (E + 63) / 64;
    k_edge_mfma<<<(ewaves + 3) / 4, 256, 0, stream>>>(pos, ei, h_bf, w1T, w2T,
                                                      mb1, mb2, agg, E);

    k_tail_mfma<<<(N + 127) / 128, 256, 0, stream>>>(x, agg, w2cT, cl2b,
                                                     wiT, ib, wlT, lb, out, N);
}

// Round 5
// 571.161 us; speedup vs baseline: 10.6381x; 1.0002x over previous
//
#include <hip/hip_runtime.h>
#include <math.h>

#define NGAUSS 50
#define NF 64
#define DIM 128

#define GSTEP (10.0f/49.0f)
#define GCOEFF (-0.5f/(GSTEP*GSTEP))
#define PIC (3.14159265358979323846f/10.0f)
#define LOG2F_ 0.69314718055994530942f

typedef short v8s __attribute__((ext_vector_type(8)));
typedef float v4f __attribute__((ext_vector_type(4)));
typedef unsigned short ushort_t;

#define MFMA(a,b,c) __builtin_amdgcn_mfma_f32_16x16x32_bf16(a, b, c, 0, 0, 0)
#define WAVE_BAR() __builtin_amdgcn_wave_barrier()

__device__ __forceinline__ unsigned short f2bf(float f) {
    unsigned u = __builtin_bit_cast(unsigned, f);
    unsigned r = (u + 0x7FFFu + ((u >> 16) & 1u)) >> 16;   // RNE
    return (unsigned short)r;
}
__device__ __forceinline__ float bf2f(unsigned short s) {
    return __builtin_bit_cast(float, ((unsigned)s) << 16);
}
__device__ __forceinline__ float ssp_f(float x) {
    return fmaxf(x, 0.0f) + __logf(1.0f + __expf(-fabsf(x))) - LOG2F_;
}

// ---------- prep: weights -> bf16, transposed to [col][k] ----------
extern "C" __global__ __launch_bounds__(256)
void k_prep(const float* __restrict__ w1, const float* __restrict__ w2,
            const float* __restrict__ cl1, const float* __restrict__ w2c,
            const float* __restrict__ wi, const float* __restrict__ wl,
            ushort_t* __restrict__ w1T, ushort_t* __restrict__ w2T,
            ushort_t* __restrict__ cl1T, ushort_t* __restrict__ w2cT,
            ushort_t* __restrict__ wiT, ushort_t* __restrict__ wlT)
{
    int id = blockIdx.x * 256 + threadIdx.x;
    int stride = gridDim.x * 256;
    for (int i = id; i < 64*64;   i += stride){ int c=i>>6, k=i&63;  w1T[i]  = f2bf(k < NGAUSS ? w1[k*64+c] : 0.0f); }
    for (int i = id; i < 64*64;   i += stride){ int c=i>>6, k=i&63;  w2T[i]  = f2bf(w2[k*64+c]); }
    for (int i = id; i < 64*128;  i += stride){ int c=i>>7, k=i&127; cl1T[i] = f2bf(cl1[k*64+c]); }
    for (int i = id; i < 128*64;  i += stride){ int c=i>>6, k=i&63;  w2cT[i] = f2bf(w2c[k*128+c]); }
    for (int i = id; i < 128*128; i += stride){ int c=i>>7, k=i&127; wiT[i]  = f2bf(wi[k*128+c]); }
    for (int i = id; i < 128*128; i += stride){ int c=i>>7, k=i&127; wlT[i]  = f2bf(wl[k*128+c]); }
}

// ---------- h = x @ conv_lin1_w -> bf16, MFMA, wave = 32 rows ----------
// Also zeroes agg for this block's rows (replaces memset dispatch).
extern "C" __global__ __launch_bounds__(256)
void k_lin1_mfma(const float* __restrict__ x, const ushort_t* __restrict__ cl1T,
                 ushort_t* __restrict__ h_bf, float* __restrict__ agg, int N)
{
    {
        int nb = blockIdx.x * 128;
        int rows = min(128, N - nb);
        if (rows > 0) {
            float4* ap = (float4*)(agg + (size_t)nb * NF);
            int tot = rows * (NF / 4);
            for (int i = threadIdx.x; i < tot; i += 256)
                ap[i] = (float4){0,0,0,0};
        }
    }

    int l = threadIdx.x & 63, w = threadIdx.x >> 6;
    int base = (blockIdx.x * 4 + w) * 32;
    int colb = l & 15, krow = (l >> 4) * 8;

    v4f C[2][4];
    #pragma unroll
    for (int m = 0; m < 2; m++)
        #pragma unroll
        for (int n = 0; n < 4; n++) C[m][n] = (v4f){0,0,0,0};

    #pragma unroll
    for (int kt = 0; kt < 4; kt++) {
        v8s am[2];
        #pragma unroll
        for (int m = 0; m < 2; m++) {
            int row = base + m*16 + colb;
            v8s a = (v8s){0,0,0,0,0,0,0,0};
            if (row < N) {
                const float4* p = (const float4*)(x + (size_t)row*DIM + kt*32 + krow);
                float4 f0 = p[0], f1 = p[1];
                a[0]=(short)f2bf(f0.x); a[1]=(short)f2bf(f0.y); a[2]=(short)f2bf(f0.z); a[3]=(short)f2bf(f0.w);
                a[4]=(short)f2bf(f1.x); a[5]=(short)f2bf(f1.y); a[6]=(short)f2bf(f1.z); a[7]=(short)f2bf(f1.w);
            }
            am[m] = a;
        }
        #pragma unroll
        for (int n = 0; n < 4; n++) {
            v8s b = *(const v8s*)(cl1T + (n*16 + colb)*DIM + kt*32 + krow);
            #pragma unroll
            for (int m = 0; m < 2; m++) C[m][n] = MFMA(am[m], b, C[m][n]);
        }
    }
    #pragma unroll
    for (int m = 0; m < 2; m++)
        #pragma unroll
        for (int n = 0; n < 4; n++)
            #pragma unroll
            for (int i = 0; i < 4; i++) {
                int row = base + m*16 + (l>>4)*4 + i;
                if (row < N) h_bf[(size_t)row*NF + n*16 + colb] = f2bf(C[m][n][i]);
            }
}

// ---------- edge kernel: MFMA MLP + coalesced native-atomic scatter ----------
extern "C" __global__ __launch_bounds__(256)
void k_edge_mfma(const float* __restrict__ pos, const int* __restrict__ ei,
                 const ushort_t* __restrict__ h_bf,
                 const ushort_t* __restrict__ w1T, const ushort_t* __restrict__ w2T,
                 const float* __restrict__ b1, const float* __restrict__ b2,
                 float* __restrict__ agg, int E)
{
    __shared__ __align__(16) char lds[4][64*128];   // per-wave 64x64 bf16, XOR-swizzled
    int l = threadIdx.x & 63, w = threadIdx.x >> 6;
    char* T = lds[w];
    size_t ebase = ((size_t)blockIdx.x * 4 + w) * 64;
    int e = (int)(ebase + l);
    bool valid = e < E;
    int s = valid ? ei[e] : 0;
    int d = valid ? ei[E + e] : 0;

    float dx = pos[3*d]   - pos[3*s];
    float dy = pos[3*d+1] - pos[3*s+1];
    float dz = pos[3*d+2] - pos[3*s+2];
    float dist = sqrtf(dx*dx + dy*dy + dz*dz);
    float Cc = valid ? 0.5f * (__cosf(dist * PIC) + 1.0f) : 0.0f;
    int cci = __builtin_bit_cast(int, Cc);

    int colb = l & 15, krow = (l >> 4) * 8;

    float b1v[4], b2v[4];
    #pragma unroll
    for (int n = 0; n < 4; n++) { b1v[n] = b1[n*16 + colb]; b2v[n] = b2[n*16 + colb]; }

    // layer 1: ea (computed directly in A-frag layout) @ w1
    v4f C1[4][4];
    #pragma unroll
    for (int m = 0; m < 4; m++)
        #pragma unroll
        for (int n = 0; n < 4; n++) C1[m][n] = (v4f){0,0,0,0};
    {
        v8s B1[2][4];
        #pragma unroll
        for (int n = 0; n < 4; n++)
            #pragma unroll
            for (int kt = 0; kt < 2; kt++)
                B1[kt][n] = *(const v8s*)(w1T + (n*16 + colb)*64 + kt*32 + krow);

        #pragma unroll
        for (int m = 0; m < 4; m++) {
            float dm = __shfl(dist, m*16 + colb);
            #pragma unroll
            for (int kt = 0; kt < 2; kt++) {
                v8s a;
                #pragma unroll
                for (int i = 0; i < 8; i++) {
                    float off = (float)(kt*32 + krow + i) * GSTEP;
                    float t = dm - off;
                    a[i] = (short)f2bf(__expf(GCOEFF * t * t));
                }
                #pragma unroll
                for (int n = 0; n < 4; n++) C1[m][n] = MFMA(a, B1[kt][n], C1[m][n]);
            }
        }
    }

    // ssp -> bf16 -> swizzled LDS tile (row=edge, col=j1)
    #pragma unroll
    for (int m = 0; m < 4; m++)
        #pragma unroll
        for (int n = 0; n < 4; n++)
            #pragma unroll
            for (int i = 0; i < 4; i++) {
                int row = m*16 + (l>>4)*4 + i;
                int col = n*16 + colb;
                float v = ssp_f(C1[m][n][i] + b1v[n]);
                *(ushort_t*)(T + row*128 + ((col*2) ^ ((row&7)<<4))) = f2bf(v);
            }
    WAVE_BAR();

    // layer 2: hid @ w2
    v4f C2[4][4];
    #pragma unroll
    for (int m = 0; m < 4; m++)
        #pragma unroll
        for (int n = 0; n < 4; n++) C2[m][n] = (v4f){0,0,0,0};
    {
        v8s B2[2][4];
        #pragma unroll
        for (int n = 0; n < 4; n++)
            #pragma unroll
            for (int kt = 0; kt < 2; kt++)
                B2[kt][n] = *(const v8s*)(w2T + (n*16 + colb)*64 + kt*32 + krow);

        #pragma unroll
        for (int m = 0; m < 4; m++) {
            int row = m*16 + colb;
            #pragma unroll
            for (int kt = 0; kt < 2; kt++) {
                v8s a = *(const v8s*)(T + row*128 + ((kt*64 + krow*2) ^ ((row&7)<<4)));
                #pragma unroll
                for (int n = 0; n < 4; n++) C2[m][n] = MFMA(a, B2[kt][n], C2[m][n]);
            }
        }
    }
    WAVE_BAR();   // all layer-2 reads precede the W overwrite below (WAR)

    // W = C2 + b2 -> bf16 -> same tile (Cc folded into scatter)
    #pragma unroll
    for (int m = 0; m < 4; m++)
        #pragma unroll
        for (int n = 0; n < 4; n++)
            #pragma unroll
            for (int i = 0; i < 4; i++) {
                int row = m*16 + (l>>4)*4 + i;
                int col = n*16 + colb;
                *(ushort_t*)(T + row*128 + ((col*2) ^ ((row&7)<<4))) = f2bf(C2[m][n][i] + b2v[n]);
            }
    WAVE_BAR();

    // scatter: lane = filter, fully unrolled; NATIVE fp32 atomic (no return,
    // no wait) -> all 64 iterations' atomics stay in flight.
    #pragma unroll
    for (int e2 = 0; e2 < 64; e2++) {
        int se = __builtin_amdgcn_readlane(s, e2);
        int de = __builtin_amdgcn_readlane(d, e2);
        float cce = __builtin_bit_cast(float, __builtin_amdgcn_readlane(cci, e2));
        float wv = bf2f(*(const ushort_t*)(T + e2*128 + ((l*2) ^ ((e2&7)<<4))));
        float hv = bf2f(h_bf[(size_t)se*NF + l]);
        unsafeAtomicAdd(agg + (size_t)de*NF + l, wv * cce * hv);
    }
}

// ---------- fused tail, MFMA, wave = 32 rows ----------
extern "C" __global__ __launch_bounds__(256)
void k_tail_mfma(const float* __restrict__ x, const float* __restrict__ agg,
                 const ushort_t* __restrict__ w2cT, const float* __restrict__ b2c,
                 const ushort_t* __restrict__ wiT,  const float* __restrict__ bi,
                 const ushort_t* __restrict__ wlT,  const float* __restrict__ bl,
                 float* __restrict__ out, int N)
{
    __shared__ __align__(16) char lds[4][32*256];   // per-wave 32x128 bf16, XOR-swizzled
    int l = threadIdx.x & 63, w = threadIdx.x >> 6;
    char* T = lds[w];
    int base = (blockIdx.x * 4 + w) * 32;
    int colb = l & 15, krow = (l >> 4) * 8;

    float b2cv[8], biv[8], blv[8];
    #pragma unroll
    for (int n = 0; n < 8; n++) {
        b2cv[n] = b2c[n*16 + colb];
        biv[n]  = bi[n*16 + colb];
        blv[n]  = bl[n*16 + colb];
    }

    // stage A: agg[32,64] @ w2cT -> ssp -> LDS
    v4f C[2][8];
    #pragma unroll
    for (int m = 0; m < 2; m++)
        #pragma unroll
        for (int n = 0; n < 8; n++) C[m][n] = (v4f){0,0,0,0};

    #pragma unroll
    for (int kt = 0; kt < 2; kt++) {
        v8s am[2];
        #pragma unroll
        for (int m = 0; m < 2; m++) {
            int row = base + m*16 + colb;
            v8s a = (v8s){0,0,0,0,0,0,0,0};
            if (row < N) {
                const float4* p = (const float4*)(agg + (size_t)row*NF + kt*32 + krow);
                float4 f0 = p[0], f1 = p[1];
                a[0]=(short)f2bf(f0.x); a[1]=(short)f2bf(f0.y); a[2]=(short)f2bf(f0.z); a[3]=(short)f2bf(f0.w);
                a[4]=(short)f2bf(f1.x); a[5]=(short)f2bf(f1.y); a[6]=(short)f2bf(f1.z); a[7]=(short)f2bf(f1.w);
            }
            am[m] = a;
        }
        #pragma unroll
        for (int n = 0; n < 8; n++) {
            v8s b = *(const v8s*)(w2cT + (n*16 + colb)*64 + kt*32 + krow);
            #pragma unroll
            for (int m = 0; m < 2; m++) C[m][n] = MFMA(am[m], b, C[m][n]);
        }
    }
    #pragma unroll
    for (int m = 0; m < 2; m++)
        #pragma unroll
        for (int n = 0; n < 8; n++)
            #pragma unroll
            for (int i = 0; i < 4; i++) {
                int rl = m*16 + (l>>4)*4 + i;
                int col = n*16 + colb;
                float v = ssp_f(C[m][n][i] + b2cv[n]);
                *(ushort_t*)(T + rl*256 + ((col*2) ^ ((rl&7)<<4))) = f2bf(v);
            }
    WAVE_BAR();

    // stage B: h2[32,128] @ wiT
    v4f D[2][8];
    #pragma unroll
    for (int m = 0; m < 2; m++)
        #pragma unroll
        for (int n = 0; n < 8; n++) D[m][n] = (v4f){0,0,0,0};

    v8s af[2][4];
    #pragma unroll
    for (int m = 0; m < 2; m++)
        #pragma unroll
        for (int kt = 0; kt < 4; kt++) {
            int rl = m*16 + colb;
            af[m][kt] = *(const v8s*)(T + rl*256 + ((kt*64 + krow*2) ^ ((rl&7)<<4)));
        }
    #pragma unroll
    for (int kt = 0; kt < 4; kt++)
        #pragma unroll
        for (int n = 0; n < 8; n++) {
            v8s b = *(const v8s*)(wiT + (n*16 + colb)*DIM + kt*32 + krow);
            #pragma unroll
            for (int m = 0; m < 2; m++) D[m][n] = MFMA(af[m][kt], b, D[m][n]);
        }
    WAVE_BAR();
    #pragma unroll
    for (int m = 0; m < 2; m++)
        #pragma unroll
        for (int n = 0; n < 8; n++)
            #pragma unroll
            for (int i = 0; i < 4; i++) {
                int rl = m*16 + (l>>4)*4 + i;
                int col = n*16 + colb;
                *(ushort_t*)(T + rl*256 + ((col*2) ^ ((rl&7)<<4))) = f2bf(D[m][n][i] + biv[n]);
            }
    WAVE_BAR();

    // stage C: h3[32,128] @ wlT -> relu -> +x -> out
    v4f G[2][8];
    #pragma unroll
    for (int m = 0; m < 2; m++)
        #pragma unroll
        for (int n = 0; n < 8; n++) G[m][n] = (v4f){0,0,0,0};

    #pragma unroll
    for (int m = 0; m < 2; m++)
        #pragma unroll
        for (int kt = 0; kt < 4; kt++) {
            int rl = m*16 + colb;
            af[m][kt] = *(const v8s*)(T + rl*256 + ((kt*64 + krow*2) ^ ((rl&7)<<4)));
        }
    #pragma unroll
    for (int kt = 0; kt < 4; kt++)
        #pragma unroll
        for (int n = 0; n < 8; n++) {
            v8s b = *(const v8s*)(wlT + (n*16 + colb)*DIM + kt*32 + krow);
            #pragma unroll
            for (int m = 0; m < 2; m++) G[m][n] = MFMA(af[m][kt], b, G[m][n]);
        }

    #pragma unroll
    for (int m = 0; m < 2; m++)
        #pragma unroll
        for (int n = 0; n < 8; n++)
            #pragma unroll
            for (int i = 0; i < 4; i++) {
                int row = base + m*16 + (l>>4)*4 + i;
                if (row < N) {
                    int col = n*16 + colb;
                    size_t o = (size_t)row*DIM + col;
                    out[o] = x[o] + fmaxf(G[m][n][i] + blv[n], 0.0f);
                }
            }
}

extern "C" void kernel_launch(void* const* d_in, const int* in_sizes, int n_in,
                              void* d_out, int out_size, void* d_ws, size_t ws_size,
                              hipStream_t stream)
{
    const float* x    = (const float*)d_in[0];
    const float* pos  = (const float*)d_in[1];
    const int*   ei   = (const int*)  d_in[2];
    const float* mw1  = (const float*)d_in[3];
    const float* mb1  = (const float*)d_in[4];
    const float* mw2  = (const float*)d_in[5];
    const float* mb2  = (const float*)d_in[6];
    const float* cl1  = (const float*)d_in[7];
    const float* cl2  = (const float*)d_in[8];
    const float* cl2b = (const float*)d_in[9];
    const float* iw   = (const float*)d_in[10];
    const float* ib   = (const float*)d_in[11];
    const float* lw   = (const float*)d_in[12];
    const float* lb   = (const float*)d_in[13];
    float* out = (float*)d_out;

    int N = in_sizes[0] / DIM;
    int E = in_sizes[2] / 2;

    char* W = (char*)d_ws;
    size_t h_bytes   = (size_t)N * NF * sizeof(ushort_t);
    size_t agg_bytes = (size_t)N * NF * sizeof(float);
    ushort_t* h_bf = (ushort_t*)W;
    float*    agg  = (float*)(W + h_bytes);
    ushort_t* wT   = (ushort_t*)(W + h_bytes + agg_bytes);
    ushort_t* w1T  = wT;
    ushort_t* w2T  = wT + 4096;
    ushort_t* cl1T = wT + 8192;
    ushort_t* w2cT = wT + 16384;
    ushort_t* wiT  = wT + 24576;
    ushort_t* wlT  = wT + 40960;

    k_prep<<<60, 256, 0, stream>>>(mw1, mw2, cl1, cl2, iw, lw,
                                   w1T, w2T, cl1T, w2cT, wiT, wlT);

    k_lin1_mfma<<<(N + 127) / 128, 256, 0, stream>>>(x, cl1T, h_bf, agg, N);

    int ewaves = (E + 63) / 64;
    k_edge_mfma<<<(ewaves + 3) / 4, 256, 0, stream>>>(pos, ei, h_bf, w1T, w2T,
                                                      mb1, mb2, agg, E);

    k_tail_mfma<<<(N + 127) / 128, 256, 0, stream>>>(x, agg, w2cT, cl2b,
                                                     wiT, ib, wlT, lb, out, N);
}

// Round 6
// 391.736 us; speedup vs baseline: 15.5107x; 1.4580x over previous
//
#include <hip/hip_runtime.h>
#include <hip/hip_fp16.h>
#include <math.h>

#define NGAUSS 50
#define NF 64
#define DIM 128

#define GSTEP (10.0f/49.0f)
#define GCOEFF (-0.5f/(GSTEP*GSTEP))
#define PIC (3.14159265358979323846f/10.0f)
#define LOG2F_ 0.69314718055994530942f

typedef short v8s __attribute__((ext_vector_type(8)));
typedef _Float16 v8h __attribute__((ext_vector_type(8)));
typedef float v4f __attribute__((ext_vector_type(4)));
typedef unsigned short ushort_t;

#define MFMA(a,b,c)  __builtin_amdgcn_mfma_f32_16x16x32_bf16(a, b, c, 0, 0, 0)
#define MFMAH(a,b,c) __builtin_amdgcn_mfma_f32_16x16x32_f16(a, b, c, 0, 0, 0)
#define WAVE_BAR() __builtin_amdgcn_wave_barrier()

__device__ __forceinline__ unsigned short f2bf(float f) {
    unsigned u = __builtin_bit_cast(unsigned, f);
    unsigned r = (u + 0x7FFFu + ((u >> 16) & 1u)) >> 16;   // RNE
    return (unsigned short)r;
}
__device__ __forceinline__ unsigned short f2h(float f) {
    _Float16 h = (_Float16)f;                              // RNE
    return __builtin_bit_cast(unsigned short, h);
}
__device__ __forceinline__ float ssp_f(float x) {
    return fmaxf(x, 0.0f) + __logf(1.0f + __expf(-fabsf(x))) - LOG2F_;
}

// ---------- prep: weights -> bf16 (w2c -> f16), transposed to [col][k] ----------
extern "C" __global__ __launch_bounds__(256)
void k_prep(const float* __restrict__ w1, const float* __restrict__ w2,
            const float* __restrict__ cl1, const float* __restrict__ w2c,
            const float* __restrict__ wi, const float* __restrict__ wl,
            ushort_t* __restrict__ w1T, ushort_t* __restrict__ w2T,
            ushort_t* __restrict__ cl1T, ushort_t* __restrict__ w2cT,
            ushort_t* __restrict__ wiT, ushort_t* __restrict__ wlT)
{
    int id = blockIdx.x * 256 + threadIdx.x;
    int stride = gridDim.x * 256;
    for (int i = id; i < 64*64;   i += stride){ int c=i>>6, k=i&63;  w1T[i]  = f2bf(k < NGAUSS ? w1[k*64+c] : 0.0f); }
    for (int i = id; i < 64*64;   i += stride){ int c=i>>6, k=i&63;  w2T[i]  = f2bf(w2[k*64+c]); }
    for (int i = id; i < 64*128;  i += stride){ int c=i>>7, k=i&127; cl1T[i] = f2bf(cl1[k*64+c]); }
    for (int i = id; i < 128*64;  i += stride){ int c=i>>6, k=i&63;  w2cT[i] = f2h(w2c[k*128+c]); }   // f16 (pairs with f16 agg)
    for (int i = id; i < 128*128; i += stride){ int c=i>>7, k=i&127; wiT[i]  = f2bf(wi[k*128+c]); }
    for (int i = id; i < 128*128; i += stride){ int c=i>>7, k=i&127; wlT[i]  = f2bf(wl[k*128+c]); }
}

// ---------- h = x @ conv_lin1_w -> f16, MFMA, wave = 32 rows ----------
// Also zeroes agg (f16) for this block's rows.
extern "C" __global__ __launch_bounds__(256)
void k_lin1_mfma(const float* __restrict__ x, const ushort_t* __restrict__ cl1T,
                 ushort_t* __restrict__ h16, ushort_t* __restrict__ agg16, int N)
{
    {
        int nb = blockIdx.x * 128;
        int rows = min(128, N - nb);
        if (rows > 0) {
            float4* ap = (float4*)(agg16 + (size_t)nb * NF);
            int tot = rows * (NF * 2 / 16);       // rows * 8 float4s
            for (int i = threadIdx.x; i < tot; i += 256)
                ap[i] = (float4){0,0,0,0};
        }
    }

    int l = threadIdx.x & 63, w = threadIdx.x >> 6;
    int base = (blockIdx.x * 4 + w) * 32;
    int colb = l & 15, krow = (l >> 4) * 8;

    v4f C[2][4];
    #pragma unroll
    for (int m = 0; m < 2; m++)
        #pragma unroll
        for (int n = 0; n < 4; n++) C[m][n] = (v4f){0,0,0,0};

    #pragma unroll
    for (int kt = 0; kt < 4; kt++) {
        v8s am[2];
        #pragma unroll
        for (int m = 0; m < 2; m++) {
            int row = base + m*16 + colb;
            v8s a = (v8s){0,0,0,0,0,0,0,0};
            if (row < N) {
                const float4* p = (const float4*)(x + (size_t)row*DIM + kt*32 + krow);
                float4 f0 = p[0], f1 = p[1];
                a[0]=(short)f2bf(f0.x); a[1]=(short)f2bf(f0.y); a[2]=(short)f2bf(f0.z); a[3]=(short)f2bf(f0.w);
                a[4]=(short)f2bf(f1.x); a[5]=(short)f2bf(f1.y); a[6]=(short)f2bf(f1.z); a[7]=(short)f2bf(f1.w);
            }
            am[m] = a;
        }
        #pragma unroll
        for (int n = 0; n < 4; n++) {
            v8s b = *(const v8s*)(cl1T + (n*16 + colb)*DIM + kt*32 + krow);
            #pragma unroll
            for (int m = 0; m < 2; m++) C[m][n] = MFMA(am[m], b, C[m][n]);
        }
    }
    #pragma unroll
    for (int m = 0; m < 2; m++)
        #pragma unroll
        for (int n = 0; n < 4; n++)
            #pragma unroll
            for (int i = 0; i < 4; i++) {
                int row = base + m*16 + (l>>4)*4 + i;
                if (row < N) h16[(size_t)row*NF + n*16 + colb] = f2h(C[m][n][i]);
            }
}

// ---------- edge kernel: MFMA MLP + packed-f16 atomic scatter ----------
extern "C" __global__ __launch_bounds__(256)
void k_edge_mfma(const float* __restrict__ pos, const int* __restrict__ ei,
                 const ushort_t* __restrict__ h16,
                 const ushort_t* __restrict__ w1T, const ushort_t* __restrict__ w2T,
                 const float* __restrict__ b1, const float* __restrict__ b2,
                 ushort_t* __restrict__ agg16, int E)
{
    __shared__ __align__(16) char lds[4][64*128];   // per-wave 64x64 x16bit, XOR-swizzled
    int l = threadIdx.x & 63, w = threadIdx.x >> 6;
    char* T = lds[w];
    size_t ebase = ((size_t)blockIdx.x * 4 + w) * 64;
    int e = (int)(ebase + l);
    bool valid = e < E;
    int s = valid ? ei[e] : 0;
    int d = valid ? ei[E + e] : 0;

    float dx = pos[3*d]   - pos[3*s];
    float dy = pos[3*d+1] - pos[3*s+1];
    float dz = pos[3*d+2] - pos[3*s+2];
    float dist = sqrtf(dx*dx + dy*dy + dz*dz);
    float Cc = valid ? 0.5f * (__cosf(dist * PIC) + 1.0f) : 0.0f;
    int cci = __builtin_bit_cast(int, Cc);

    int colb = l & 15, krow = (l >> 4) * 8;

    float b1v[4], b2v[4];
    #pragma unroll
    for (int n = 0; n < 4; n++) { b1v[n] = b1[n*16 + colb]; b2v[n] = b2[n*16 + colb]; }

    // layer 1: ea (computed directly in A-frag layout) @ w1
    v4f C1[4][4];
    #pragma unroll
    for (int m = 0; m < 4; m++)
        #pragma unroll
        for (int n = 0; n < 4; n++) C1[m][n] = (v4f){0,0,0,0};
    {
        v8s B1[2][4];
        #pragma unroll
        for (int n = 0; n < 4; n++)
            #pragma unroll
            for (int kt = 0; kt < 2; kt++)
                B1[kt][n] = *(const v8s*)(w1T + (n*16 + colb)*64 + kt*32 + krow);

        #pragma unroll
        for (int m = 0; m < 4; m++) {
            float dm = __shfl(dist, m*16 + colb);
            #pragma unroll
            for (int kt = 0; kt < 2; kt++) {
                v8s a;
                #pragma unroll
                for (int i = 0; i < 8; i++) {
                    float off = (float)(kt*32 + krow + i) * GSTEP;
                    float t = dm - off;
                    a[i] = (short)f2bf(__expf(GCOEFF * t * t));
                }
                #pragma unroll
                for (int n = 0; n < 4; n++) C1[m][n] = MFMA(a, B1[kt][n], C1[m][n]);
            }
        }
    }

    // ssp -> bf16 -> swizzled LDS tile (row=edge, col=j1)
    #pragma unroll
    for (int m = 0; m < 4; m++)
        #pragma unroll
        for (int n = 0; n < 4; n++)
            #pragma unroll
            for (int i = 0; i < 4; i++) {
                int row = m*16 + (l>>4)*4 + i;
                int col = n*16 + colb;
                float v = ssp_f(C1[m][n][i] + b1v[n]);
                *(ushort_t*)(T + row*128 + ((col*2) ^ ((row&7)<<4))) = f2bf(v);
            }
    WAVE_BAR();

    // layer 2: hid @ w2
    v4f C2[4][4];
    #pragma unroll
    for (int m = 0; m < 4; m++)
        #pragma unroll
        for (int n = 0; n < 4; n++) C2[m][n] = (v4f){0,0,0,0};
    {
        v8s B2[2][4];
        #pragma unroll
        for (int n = 0; n < 4; n++)
            #pragma unroll
            for (int kt = 0; kt < 2; kt++)
                B2[kt][n] = *(const v8s*)(w2T + (n*16 + colb)*64 + kt*32 + krow);

        #pragma unroll
        for (int m = 0; m < 4; m++) {
            int row = m*16 + colb;
            #pragma unroll
            for (int kt = 0; kt < 2; kt++) {
                v8s a = *(const v8s*)(T + row*128 + ((kt*64 + krow*2) ^ ((row&7)<<4)));
                #pragma unroll
                for (int n = 0; n < 4; n++) C2[m][n] = MFMA(a, B2[kt][n], C2[m][n]);
            }
        }
    }
    WAVE_BAR();   // all layer-2 reads precede the W overwrite below (WAR)

    // W = C2 + b2 -> f16 -> same tile (Cc folded into scatter)
    #pragma unroll
    for (int m = 0; m < 4; m++)
        #pragma unroll
        for (int n = 0; n < 4; n++)
            #pragma unroll
            for (int i = 0; i < 4; i++) {
                int row = m*16 + (l>>4)*4 + i;
                int col = n*16 + colb;
                *(ushort_t*)(T + row*128 + ((col*2) ^ ((row&7)<<4))) = f2h(C2[m][n][i] + b2v[n]);
            }
    WAVE_BAR();

    // scatter: 2 edges/iter (lane>>5 selects edge), lane&31 = filter pair.
    // Packed f16 atomic: 2 values per dword-RMW -> half the memory-side
    // atomic line operations vs fp32.
    int jj = l & 31;
    int hsel = l >> 5;                       // 0: even edge, 1: odd edge
    #pragma unroll
    for (int e2 = 0; e2 < 32; e2++) {
        int sA = __builtin_amdgcn_readlane(s, 2*e2);
        int sB = __builtin_amdgcn_readlane(s, 2*e2 + 1);
        int dA = __builtin_amdgcn_readlane(d, 2*e2);
        int dB = __builtin_amdgcn_readlane(d, 2*e2 + 1);
        int cA = __builtin_amdgcn_readlane(cci, 2*e2);
        int cB = __builtin_amdgcn_readlane(cci, 2*e2 + 1);
        int ssel = hsel ? sB : sA;
        int dsel = hsel ? dB : dA;
        float csel = __builtin_bit_cast(float, hsel ? cB : cA);

        int epair = 2*e2 + hsel;
        unsigned wbits = *(const unsigned*)(T + epair*128 + ((jj*4) ^ ((epair&7)<<4)));
        unsigned hbits = *(const unsigned*)(h16 + (size_t)ssel*NF + 2*jj);
        __half2 wv = __builtin_bit_cast(__half2, wbits);
        __half2 hv = __builtin_bit_cast(__half2, hbits);
        __half ch = __float2half(csel);
        __half2 cv = __halves2half2(ch, ch);
        __half2 prod = __hmul2(__hmul2(wv, hv), cv);
        unsafeAtomicAdd((__half2*)(agg16 + (size_t)dsel*NF + 2*jj), prod);
    }
}

// ---------- fused tail, MFMA, wave = 32 rows ----------
extern "C" __global__ __launch_bounds__(256)
void k_tail_mfma(const float* __restrict__ x, const ushort_t* __restrict__ agg16,
                 const ushort_t* __restrict__ w2cT, const float* __restrict__ b2c,
                 const ushort_t* __restrict__ wiT,  const float* __restrict__ bi,
                 const ushort_t* __restrict__ wlT,  const float* __restrict__ bl,
                 float* __restrict__ out, int N)
{
    __shared__ __align__(16) char lds[4][32*256];   // per-wave 32x128 bf16, XOR-swizzled
    int l = threadIdx.x & 63, w = threadIdx.x >> 6;
    char* T = lds[w];
    int base = (blockIdx.x * 4 + w) * 32;
    int colb = l & 15, krow = (l >> 4) * 8;

    float b2cv[8], biv[8], blv[8];
    #pragma unroll
    for (int n = 0; n < 8; n++) {
        b2cv[n] = b2c[n*16 + colb];
        biv[n]  = bi[n*16 + colb];
        blv[n]  = bl[n*16 + colb];
    }

    // stage A: agg[32,64](f16) @ w2cT(f16) -> ssp -> LDS  (f16 MFMA, no convert)
    v4f C[2][8];
    #pragma unroll
    for (int m = 0; m < 2; m++)
        #pragma unroll
        for (int n = 0; n < 8; n++) C[m][n] = (v4f){0,0,0,0};

    #pragma unroll
    for (int kt = 0; kt < 2; kt++) {
        v8h am[2];
        #pragma unroll
        for (int m = 0; m < 2; m++) {
            int row = base + m*16 + colb;
            v8h a = (v8h){0,0,0,0,0,0,0,0};
            if (row < N) a = *(const v8h*)(agg16 + (size_t)row*NF + kt*32 + krow);
            am[m] = a;
        }
        #pragma unroll
        for (int n = 0; n < 8; n++) {
            v8h b = *(const v8h*)(w2cT + (n*16 + colb)*64 + kt*32 + krow);
            #pragma unroll
            for (int m = 0; m < 2; m++) C[m][n] = MFMAH(am[m], b, C[m][n]);
        }
    }
    #pragma unroll
    for (int m = 0; m < 2; m++)
        #pragma unroll
        for (int n = 0; n < 8; n++)
            #pragma unroll
            for (int i = 0; i < 4; i++) {
                int rl = m*16 + (l>>4)*4 + i;
                int col = n*16 + colb;
                float v = ssp_f(C[m][n][i] + b2cv[n]);
                *(ushort_t*)(T + rl*256 + ((col*2) ^ ((rl&7)<<4))) = f2bf(v);
            }
    WAVE_BAR();

    // stage B: h2[32,128] @ wiT
    v4f D[2][8];
    #pragma unroll
    for (int m = 0; m < 2; m++)
        #pragma unroll
        for (int n = 0; n < 8; n++) D[m][n] = (v4f){0,0,0,0};

    v8s af[2][4];
    #pragma unroll
    for (int m = 0; m < 2; m++)
        #pragma unroll
        for (int kt = 0; kt < 4; kt++) {
            int rl = m*16 + colb;
            af[m][kt] = *(const v8s*)(T + rl*256 + ((kt*64 + krow*2) ^ ((rl&7)<<4)));
        }
    #pragma unroll
    for (int kt = 0; kt < 4; kt++)
        #pragma unroll
        for (int n = 0; n < 8; n++) {
            v8s b = *(const v8s*)(wiT + (n*16 + colb)*DIM + kt*32 + krow);
            #pragma unroll
            for (int m = 0; m < 2; m++) D[m][n] = MFMA(af[m][kt], b, D[m][n]);
        }
    WAVE_BAR();
    #pragma unroll
    for (int m = 0; m < 2; m++)
        #pragma unroll
        for (int n = 0; n < 8; n++)
            #pragma unroll
            for (int i = 0; i < 4; i++) {
                int rl = m*16 + (l>>4)*4 + i;
                int col = n*16 + colb;
                *(ushort_t*)(T + rl*256 + ((col*2) ^ ((rl&7)<<4))) = f2bf(D[m][n][i] + biv[n]);
            }
    WAVE_BAR();

    // stage C: h3[32,128] @ wlT -> relu -> +x -> out
    v4f G[2][8];
    #pragma unroll
    for (int m = 0; m < 2; m++)
        #pragma unroll
        for (int n = 0; n < 8; n++) G[m][n] = (v4f){0,0,0,0};

    #pragma unroll
    for (int m = 0; m < 2; m++)
        #pragma unroll
        for (int kt = 0; kt < 4; kt++) {
            int rl = m*16 + colb;
            af[m][kt] = *(const v8s*)(T + rl*256 + ((kt*64 + krow*2) ^ ((rl&7)<<4)));
        }
    #pragma unroll
    for (int kt = 0; kt < 4; kt++)
        #pragma unroll
        for (int n = 0; n < 8; n++) {
            v8s b = *(const v8s*)(wlT + (n*16 + colb)*DIM + kt*32 + krow);
            #pragma unroll
            for (int m = 0; m < 2; m++) G[m][n] = MFMA(af[m][kt], b, G[m][n]);
        }

    #pragma unroll
    for (int m = 0; m < 2; m++)
        #pragma unroll
        for (int n = 0; n < 8; n++)
            #pragma unroll
            for (int i = 0; i < 4; i++) {
                int row = base + m*16 + (l>>4)*4 + i;
                if (row < N) {
                    int col = n*16 + colb;
                    size_t o = (size_t)row*DIM + col;
                    out[o] = x[o] + fmaxf(G[m][n][i] + blv[n], 0.0f);
                }
            }
}

extern "C" void kernel_launch(void* const* d_in, const int* in_sizes, int n_in,
                              void* d_out, int out_size, void* d_ws, size_t ws_size,
                              hipStream_t stream)
{
    const float* x    = (const float*)d_in[0];
    const float* pos  = (const float*)d_in[1];
    const int*   ei   = (const int*)  d_in[2];
    const float* mw1  = (const float*)d_in[3];
    const float* mb1  = (const float*)d_in[4];
    const float* mw2  = (const float*)d_in[5];
    const float* mb2  = (const float*)d_in[6];
    const float* cl1  = (const float*)d_in[7];
    const float* cl2  = (const float*)d_in[8];
    const float* cl2b = (const float*)d_in[9];
    const float* iw   = (const float*)d_in[10];
    const float* ib   = (const float*)d_in[11];
    const float* lw   = (const float*)d_in[12];
    const float* lb   = (const float*)d_in[13];
    float* out = (float*)d_out;

    int N = in_sizes[0] / DIM;
    int E = in_sizes[2] / 2;

    char* W = (char*)d_ws;
    size_t h_bytes   = (size_t)N * NF * sizeof(ushort_t);
    size_t agg_bytes = (size_t)N * NF * sizeof(ushort_t);
    ushort_t* h16   = (ushort_t*)W;
    ushort_t* agg16 = (ushort_t*)(W + h_bytes);
    ushort_t* wT    = (ushort_t*)(W + h_bytes + agg_bytes);
    ushort_t* w1T  = wT;
    ushort_t* w2T  = wT + 4096;
    ushort_t* cl1T = wT + 8192;
    ushort_t* w2cT = wT + 16384;
    ushort_t* wiT  = wT + 24576;
    ushort_t* wlT  = wT + 40960;

    k_prep<<<60, 256, 0, stream>>>(mw1, mw2, cl1, cl2, iw, lw,
                                   w1T, w2T, cl1T, w2cT, wiT, wlT);

    k_lin1_mfma<<<(N + 127) / 128, 256, 0, stream>>>(x, cl1T, h16, agg16, N);

    int ewaves = (E + 63) / 64;
    k_edge_mfma<<<(ewaves + 3) / 4, 256, 0, stream>>>(pos, ei, h16, w1T, w2T,
                                                      mb1, mb2, agg16, E);

    k_tail_mfma<<<(N + 127) / 128, 256, 0, stream>>>(x, agg16, w2cT, cl2b,
                                                     wiT, ib, wlT, lb, out, N);
}

// Round 7
// 388.436 us; speedup vs baseline: 15.6425x; 1.0085x over previous
//
#include <hip/hip_runtime.h>
#include <hip/hip_fp16.h>
#include <math.h>

#define NGAUSS 50
#define NF 64
#define DIM 128

#define GSTEP (10.0f/49.0f)
#define GCOEFF (-0.5f/(GSTEP*GSTEP))
#define INV_STEP (49.0f/10.0f)
#define EM1 0.36787944117144233f
#define PIC (3.14159265358979323846f/10.0f)
#define LOG2F_ 0.69314718055994530942f

typedef short v8s __attribute__((ext_vector_type(8)));
typedef _Float16 v8h __attribute__((ext_vector_type(8)));
typedef float v4f __attribute__((ext_vector_type(4)));
typedef unsigned short ushort_t;

#define MFMA(a,b,c)  __builtin_amdgcn_mfma_f32_16x16x32_bf16(a, b, c, 0, 0, 0)
#define MFMAH(a,b,c) __builtin_amdgcn_mfma_f32_16x16x32_f16(a, b, c, 0, 0, 0)
#define WAVE_BAR() __builtin_amdgcn_wave_barrier()

__device__ __forceinline__ unsigned short f2bf(float f) {
    unsigned u = __builtin_bit_cast(unsigned, f);
    unsigned r = (u + 0x7FFFu + ((u >> 16) & 1u)) >> 16;   // RNE
    return (unsigned short)r;
}
__device__ __forceinline__ unsigned cvt_pk_bf16(float lo, float hi) {
    unsigned r;
    asm("v_cvt_pk_bf16_f32 %0, %1, %2" : "=v"(r) : "v"(lo), "v"(hi));
    return r;
}
__device__ __forceinline__ unsigned short f2h(float f) {
    _Float16 h = (_Float16)f;                              // v_cvt_f16_f32
    return __builtin_bit_cast(unsigned short, h);
}
__device__ __forceinline__ float ssp_f(float x) {
    return fmaxf(x, 0.0f) + __logf(1.0f + __expf(-fabsf(x))) - LOG2F_;
}

// ---------- prep: weights -> bf16 (w2c -> f16), transposed to [col][k] ----------
extern "C" __global__ __launch_bounds__(256)
void k_prep(const float* __restrict__ w1, const float* __restrict__ w2,
            const float* __restrict__ cl1, const float* __restrict__ w2c,
            const float* __restrict__ wi, const float* __restrict__ wl,
            ushort_t* __restrict__ w1T, ushort_t* __restrict__ w2T,
            ushort_t* __restrict__ cl1T, ushort_t* __restrict__ w2cT,
            ushort_t* __restrict__ wiT, ushort_t* __restrict__ wlT)
{
    int id = blockIdx.x * 256 + threadIdx.x;
    int stride = gridDim.x * 256;
    for (int i = id; i < 64*64;   i += stride){ int c=i>>6, k=i&63;  w1T[i]  = f2bf(k < NGAUSS ? w1[k*64+c] : 0.0f); }
    for (int i = id; i < 64*64;   i += stride){ int c=i>>6, k=i&63;  w2T[i]  = f2bf(w2[k*64+c]); }
    for (int i = id; i < 64*128;  i += stride){ int c=i>>7, k=i&127; cl1T[i] = f2bf(cl1[k*64+c]); }
    for (int i = id; i < 128*64;  i += stride){ int c=i>>6, k=i&63;  w2cT[i] = f2h(w2c[k*128+c]); }   // f16 (pairs with f16 agg)
    for (int i = id; i < 128*128; i += stride){ int c=i>>7, k=i&127; wiT[i]  = f2bf(wi[k*128+c]); }
    for (int i = id; i < 128*128; i += stride){ int c=i>>7, k=i&127; wlT[i]  = f2bf(wl[k*128+c]); }
}

// ---------- h = x @ conv_lin1_w -> f16, MFMA, wave = 32 rows ----------
// Also zeroes agg (f16) for this block's rows.
extern "C" __global__ __launch_bounds__(256)
void k_lin1_mfma(const float* __restrict__ x, const ushort_t* __restrict__ cl1T,
                 ushort_t* __restrict__ h16, ushort_t* __restrict__ agg16, int N)
{
    {
        int nb = blockIdx.x * 128;
        int rows = min(128, N - nb);
        if (rows > 0) {
            float4* ap = (float4*)(agg16 + (size_t)nb * NF);
            int tot = rows * (NF * 2 / 16);       // rows * 8 float4s
            for (int i = threadIdx.x; i < tot; i += 256)
                ap[i] = (float4){0,0,0,0};
        }
    }

    int l = threadIdx.x & 63, w = threadIdx.x >> 6;
    int base = (blockIdx.x * 4 + w) * 32;
    int colb = l & 15, krow = (l >> 4) * 8;

    v4f C[2][4];
    #pragma unroll
    for (int m = 0; m < 2; m++)
        #pragma unroll
        for (int n = 0; n < 4; n++) C[m][n] = (v4f){0,0,0,0};

    #pragma unroll
    for (int kt = 0; kt < 4; kt++) {
        v8s am[2];
        #pragma unroll
        for (int m = 0; m < 2; m++) {
            int row = base + m*16 + colb;
            union { v8s v; unsigned d[4]; } A;
            A.d[0]=0; A.d[1]=0; A.d[2]=0; A.d[3]=0;
            if (row < N) {
                const float4* p = (const float4*)(x + (size_t)row*DIM + kt*32 + krow);
                float4 f0 = p[0], f1 = p[1];
                A.d[0] = cvt_pk_bf16(f0.x, f0.y);
                A.d[1] = cvt_pk_bf16(f0.z, f0.w);
                A.d[2] = cvt_pk_bf16(f1.x, f1.y);
                A.d[3] = cvt_pk_bf16(f1.z, f1.w);
            }
            am[m] = A.v;
        }
        #pragma unroll
        for (int n = 0; n < 4; n++) {
            v8s b = *(const v8s*)(cl1T + (n*16 + colb)*DIM + kt*32 + krow);
            #pragma unroll
            for (int m = 0; m < 2; m++) C[m][n] = MFMA(am[m], b, C[m][n]);
        }
    }
    #pragma unroll
    for (int m = 0; m < 2; m++)
        #pragma unroll
        for (int n = 0; n < 4; n++)
            #pragma unroll
            for (int i = 0; i < 4; i++) {
                int row = base + m*16 + (l>>4)*4 + i;
                if (row < N) h16[(size_t)row*NF + n*16 + colb] = f2h(C[m][n][i]);
            }
}

// ---------- edge kernel: MFMA MLP + packed-f16 atomic scatter ----------
extern "C" __global__ __launch_bounds__(256)
void k_edge_mfma(const float* __restrict__ pos, const int* __restrict__ ei,
                 const ushort_t* __restrict__ h16,
                 const ushort_t* __restrict__ w1T, const ushort_t* __restrict__ w2T,
                 const float* __restrict__ b1, const float* __restrict__ b2,
                 ushort_t* __restrict__ agg16, int E)
{
    __shared__ __align__(16) char lds[4][64*128];   // per-wave 64x64 x16bit, XOR-swizzled
    int l = threadIdx.x & 63, w = threadIdx.x >> 6;
    char* T = lds[w];
    size_t ebase = ((size_t)blockIdx.x * 4 + w) * 64;
    int e = (int)(ebase + l);
    bool valid = e < E;
    int s = valid ? ei[e] : 0;
    int d = valid ? ei[E + e] : 0;

    float dx = pos[3*d]   - pos[3*s];
    float dy = pos[3*d+1] - pos[3*s+1];
    float dz = pos[3*d+2] - pos[3*s+2];
    float dist = sqrtf(dx*dx + dy*dy + dz*dz);
    float Cc = valid ? 0.5f * (__cosf(dist * PIC) + 1.0f) : 0.0f;
    int cci = __builtin_bit_cast(int, Cc);

    int colb = l & 15, krow = (l >> 4) * 8;

    float b1v[4], b2v[4];
    #pragma unroll
    for (int n = 0; n < 4; n++) { b1v[n] = b1[n*16 + colb]; b2v[n] = b2[n*16 + colb]; }

    // layer 1: ea (chain-exp, built directly in A-frag layout) @ w1
    // exp(C(t-iΔ)²) = exp(Ct²)·Π u;  u₀ = exp(t/Δ − ½), u_{i+1} = u_i·e⁻¹.
    // Window (7Δ=1.43) < underflow boundary (|t|>2.70), so a dead chain
    // start implies all true values < 4e-9 — negligible.
    v4f C1[4][4];
    #pragma unroll
    for (int m = 0; m < 4; m++)
        #pragma unroll
        for (int n = 0; n < 4; n++) C1[m][n] = (v4f){0,0,0,0};
    {
        v8s B1[2][4];
        #pragma unroll
        for (int n = 0; n < 4; n++)
            #pragma unroll
            for (int kt = 0; kt < 2; kt++)
                B1[kt][n] = *(const v8s*)(w1T + (n*16 + colb)*64 + kt*32 + krow);

        #pragma unroll
        for (int m = 0; m < 4; m++) {
            float dm = __shfl(dist, m*16 + colb);
            #pragma unroll
            for (int kt = 0; kt < 2; kt++) {
                int m0 = kt*32 + krow;
                float t0 = dm - (float)m0 * GSTEP;
                float e0 = __expf(GCOEFF * t0 * t0);
                float u  = __expf(fmaf(dm, INV_STEP, -((float)m0 + 0.5f)));
                float e1 = e0 * u; u *= EM1;
                float e2 = e1 * u; u *= EM1;
                float e3 = e2 * u; u *= EM1;
                float e4 = e3 * u; u *= EM1;
                float e5 = e4 * u; u *= EM1;
                float e6 = e5 * u; u *= EM1;
                float e7 = e6 * u;
                union { v8s v; unsigned dw[4]; } A;
                A.dw[0] = cvt_pk_bf16(e0, e1);
                A.dw[1] = cvt_pk_bf16(e2, e3);
                A.dw[2] = cvt_pk_bf16(e4, e5);
                A.dw[3] = cvt_pk_bf16(e6, e7);
                #pragma unroll
                for (int n = 0; n < 4; n++) C1[m][n] = MFMA(A.v, B1[kt][n], C1[m][n]);
            }
        }
    }

    // ssp -> bf16 -> swizzled LDS tile (row=edge, col=j1)
    #pragma unroll
    for (int m = 0; m < 4; m++)
        #pragma unroll
        for (int n = 0; n < 4; n++)
            #pragma unroll
            for (int i = 0; i < 4; i++) {
                int row = m*16 + (l>>4)*4 + i;
                int col = n*16 + colb;
                float v = ssp_f(C1[m][n][i] + b1v[n]);
                *(ushort_t*)(T + row*128 + ((col*2) ^ ((row&7)<<4))) = f2bf(v);
            }
    WAVE_BAR();

    // layer 2: hid @ w2
    v4f C2[4][4];
    #pragma unroll
    for (int m = 0; m < 4; m++)
        #pragma unroll
        for (int n = 0; n < 4; n++) C2[m][n] = (v4f){0,0,0,0};
    {
        v8s B2[2][4];
        #pragma unroll
        for (int n = 0; n < 4; n++)
            #pragma unroll
            for (int kt = 0; kt < 2; kt++)
                B2[kt][n] = *(const v8s*)(w2T + (n*16 + colb)*64 + kt*32 + krow);

        #pragma unroll
        for (int m = 0; m < 4; m++) {
            int row = m*16 + colb;
            #pragma unroll
            for (int kt = 0; kt < 2; kt++) {
                v8s a = *(const v8s*)(T + row*128 + ((kt*64 + krow*2) ^ ((row&7)<<4)));
                #pragma unroll
                for (int n = 0; n < 4; n++) C2[m][n] = MFMA(a, B2[kt][n], C2[m][n]);
            }
        }
    }
    WAVE_BAR();   // all layer-2 reads precede the W overwrite below (WAR)

    // W = C2 + b2 -> f16 -> same tile (Cc folded into scatter)
    #pragma unroll
    for (int m = 0; m < 4; m++)
        #pragma unroll
        for (int n = 0; n < 4; n++)
            #pragma unroll
            for (int i = 0; i < 4; i++) {
                int row = m*16 + (l>>4)*4 + i;
                int col = n*16 + colb;
                *(ushort_t*)(T + row*128 + ((col*2) ^ ((row&7)<<4))) = f2h(C2[m][n][i] + b2v[n]);
            }
    WAVE_BAR();

    // scatter: 2 edges/iter (lane>>5 selects edge), lane&31 = filter pair.
    // Packed f16 atomic: 2 values per dword-RMW -> 2x 64B lines per edge
    // (structural minimum for a 128B payload).
    int jj = l & 31;
    int hsel = l >> 5;                       // 0: even edge, 1: odd edge
    #pragma unroll
    for (int e2 = 0; e2 < 32; e2++) {
        int sA = __builtin_amdgcn_readlane(s, 2*e2);
        int sB = __builtin_amdgcn_readlane(s, 2*e2 + 1);
        int dA = __builtin_amdgcn_readlane(d, 2*e2);
        int dB = __builtin_amdgcn_readlane(d, 2*e2 + 1);
        int cA = __builtin_amdgcn_readlane(cci, 2*e2);
        int cB = __builtin_amdgcn_readlane(cci, 2*e2 + 1);
        int ssel = hsel ? sB : sA;
        int dsel = hsel ? dB : dA;
        float csel = __builtin_bit_cast(float, hsel ? cB : cA);

        int epair = 2*e2 + hsel;
        unsigned wbits = *(const unsigned*)(T + epair*128 + ((jj*4) ^ ((epair&7)<<4)));
        unsigned hbits = *(const unsigned*)(h16 + (size_t)ssel*NF + 2*jj);
        __half2 wv = __builtin_bit_cast(__half2, wbits);
        __half2 hv = __builtin_bit_cast(__half2, hbits);
        __half ch = __float2half(csel);
        __half2 cv = __halves2half2(ch, ch);
        __half2 prod = __hmul2(__hmul2(wv, hv), cv);
        unsafeAtomicAdd((__half2*)(agg16 + (size_t)dsel*NF + 2*jj), prod);
    }
}

// ---------- fused tail, MFMA, wave = 32 rows ----------
extern "C" __global__ __launch_bounds__(256)
void k_tail_mfma(const float* __restrict__ x, const ushort_t* __restrict__ agg16,
                 const ushort_t* __restrict__ w2cT, const float* __restrict__ b2c,
                 const ushort_t* __restrict__ wiT,  const float* __restrict__ bi,
                 const ushort_t* __restrict__ wlT,  const float* __restrict__ bl,
                 float* __restrict__ out, int N)
{
    __shared__ __align__(16) char lds[4][32*256];   // per-wave 32x128 bf16, XOR-swizzled
    int l = threadIdx.x & 63, w = threadIdx.x >> 6;
    char* T = lds[w];
    int base = (blockIdx.x * 4 + w) * 32;
    int colb = l & 15, krow = (l >> 4) * 8;

    float b2cv[8], biv[8], blv[8];
    #pragma unroll
    for (int n = 0; n < 8; n++) {
        b2cv[n] = b2c[n*16 + colb];
        biv[n]  = bi[n*16 + colb];
        blv[n]  = bl[n*16 + colb];
    }

    // stage A: agg[32,64](f16) @ w2cT(f16) -> ssp -> LDS  (f16 MFMA, no convert)
    v4f C[2][8];
    #pragma unroll
    for (int m = 0; m < 2; m++)
        #pragma unroll
        for (int n = 0; n < 8; n++) C[m][n] = (v4f){0,0,0,0};

    #pragma unroll
    for (int kt = 0; kt < 2; kt++) {
        v8h am[2];
        #pragma unroll
        for (int m = 0; m < 2; m++) {
            int row = base + m*16 + colb;
            v8h a = (v8h){0,0,0,0,0,0,0,0};
            if (row < N) a = *(const v8h*)(agg16 + (size_t)row*NF + kt*32 + krow);
            am[m] = a;
        }
        #pragma unroll
        for (int n = 0; n < 8; n++) {
            v8h b = *(const v8h*)(w2cT + (n*16 + colb)*64 + kt*32 + krow);
            #pragma unroll
            for (int m = 0; m < 2; m++) C[m][n] = MFMAH(am[m], b, C[m][n]);
        }
    }
    #pragma unroll
    for (int m = 0; m < 2; m++)
        #pragma unroll
        for (int n = 0; n < 8; n++)
            #pragma unroll
            for (int i = 0; i < 4; i++) {
                int rl = m*16 + (l>>4)*4 + i;
                int col = n*16 + colb;
                float v = ssp_f(C[m][n][i] + b2cv[n]);
                *(ushort_t*)(T + rl*256 + ((col*2) ^ ((rl&7)<<4))) = f2bf(v);
            }
    WAVE_BAR();

    // stage B: h2[32,128] @ wiT
    v4f D[2][8];
    #pragma unroll
    for (int m = 0; m < 2; m++)
        #pragma unroll
        for (int n = 0; n < 8; n++) D[m][n] = (v4f){0,0,0,0};

    v8s af[2][4];
    #pragma unroll
    for (int m = 0; m < 2; m++)
        #pragma unroll
        for (int kt = 0; kt < 4; kt++) {
            int rl = m*16 + colb;
            af[m][kt] = *(const v8s*)(T + rl*256 + ((kt*64 + krow*2) ^ ((rl&7)<<4)));
        }
    #pragma unroll
    for (int kt = 0; kt < 4; kt++)
        #pragma unroll
        for (int n = 0; n < 8; n++) {
            v8s b = *(const v8s*)(wiT + (n*16 + colb)*DIM + kt*32 + krow);
            #pragma unroll
            for (int m = 0; m < 2; m++) D[m][n] = MFMA(af[m][kt], b, D[m][n]);
        }
    WAVE_BAR();
    #pragma unroll
    for (int m = 0; m < 2; m++)
        #pragma unroll
        for (int n = 0; n < 8; n++)
            #pragma unroll
            for (int i = 0; i < 4; i++) {
                int rl = m*16 + (l>>4)*4 + i;
                int col = n*16 + colb;
                *(ushort_t*)(T + rl*256 + ((col*2) ^ ((rl&7)<<4))) = f2bf(D[m][n][i] + biv[n]);
            }
    WAVE_BAR();

    // stage C: h3[32,128] @ wlT -> relu -> +x -> out
    v4f G[2][8];
    #pragma unroll
    for (int m = 0; m < 2; m++)
        #pragma unroll
        for (int n = 0; n < 8; n++) G[m][n] = (v4f){0,0,0,0};

    #pragma unroll
    for (int m = 0; m < 2; m++)
        #pragma unroll
        for (int kt = 0; kt < 4; kt++) {
            int rl = m*16 + colb;
            af[m][kt] = *(const v8s*)(T + rl*256 + ((kt*64 + krow*2) ^ ((rl&7)<<4)));
        }
    #pragma unroll
    for (int kt = 0; kt < 4; kt++)
        #pragma unroll
        for (int n = 0; n < 8; n++) {
            v8s b = *(const v8s*)(wlT + (n*16 + colb)*DIM + kt*32 + krow);
            #pragma unroll
            for (int m = 0; m < 2; m++) G[m][n] = MFMA(af[m][kt], b, G[m][n]);
        }

    #pragma unroll
    for (int m = 0; m < 2; m++)
        #pragma unroll
        for (int n = 0; n < 8; n++)
            #pragma unroll
            for (int i = 0; i < 4; i++) {
                int row = base + m*16 + (l>>4)*4 + i;
                if (row < N) {
                    int col = n*16 + colb;
                    size_t o = (size_t)row*DIM + col;
                    out[o] = x[o] + fmaxf(G[m][n][i] + blv[n], 0.0f);
                }
            }
}

extern "C" void kernel_launch(void* const* d_in, const int* in_sizes, int n_in,
                              void* d_out, int out_size, void* d_ws, size_t ws_size,
                              hipStream_t stream)
{
    const float* x    = (const float*)d_in[0];
    const float* pos  = (const float*)d_in[1];
    const int*   ei   = (const int*)  d_in[2];
    const float* mw1  = (const float*)d_in[3];
    const float* mb1  = (const float*)d_in[4];
    const float* mw2  = (const float*)d_in[5];
    const float* mb2  = (const float*)d_in[6];
    const float* cl1  = (const float*)d_in[7];
    const float* cl2  = (const float*)d_in[8];
    const float* cl2b = (const float*)d_in[9];
    const float* iw   = (const float*)d_in[10];
    const float* ib   = (const float*)d_in[11];
    const float* lw   = (const float*)d_in[12];
    const float* lb   = (const float*)d_in[13];
    float* out = (float*)d_out;

    int N = in_sizes[0] / DIM;
    int E = in_sizes[2] / 2;

    char* W = (char*)d_ws;
    size_t h_bytes   = (size_t)N * NF * sizeof(ushort_t);
    size_t agg_bytes = (size_t)N * NF * sizeof(ushort_t);
    ushort_t* h16   = (ushort_t*)W;
    ushort_t* agg16 = (ushort_t*)(W + h_bytes);
    ushort_t* wT    = (ushort_t*)(W + h_bytes + agg_bytes);
    ushort_t* w1T  = wT;
    ushort_t* w2T  = wT + 4096;
    ushort_t* cl1T = wT + 8192;
    ushort_t* w2cT = wT + 16384;
    ushort_t* wiT  = wT + 24576;
    ushort_t* wlT  = wT + 40960;

    k_prep<<<60, 256, 0, stream>>>(mw1, mw2, cl1, cl2, iw, lw,
                                   w1T, w2T, cl1T, w2cT, wiT, wlT);

    k_lin1_mfma<<<(N + 127) / 128, 256, 0, stream>>>(x, cl1T, h16, agg16, N);

    int ewaves = (E + 63) / 64;
    k_edge_mfma<<<(ewaves + 3) / 4, 256, 0, stream>>>(pos, ei, h16, w1T, w2T,
                                                      mb1, mb2, agg16, E);

    k_tail_mfma<<<(N + 127) / 128, 256, 0, stream>>>(x, agg16, w2cT, cl2b,
                                                     wiT, ib, wlT, lb, out, N);
}

// Round 8
// 289.661 us; speedup vs baseline: 20.9766x; 1.3410x over previous
//
#include <hip/hip_runtime.h>
#include <hip/hip_fp16.h>
#include <math.h>

#define NGAUSS 50
#define NF 64
#define DIM 128

#define GSTEP (10.0f/49.0f)
#define GCOEFF (-0.5f/(GSTEP*GSTEP))
#define INV_STEP (49.0f/10.0f)
#define EM1 0.36787944117144233f
#define PIC (3.14159265358979323846f/10.0f)
#define LOG2F_ 0.69314718055994530942f

typedef short v8s __attribute__((ext_vector_type(8)));
typedef _Float16 v8h __attribute__((ext_vector_type(8)));
typedef float v4f __attribute__((ext_vector_type(4)));
typedef unsigned short ushort_t;

#define MFMA(a,b,c)  __builtin_amdgcn_mfma_f32_16x16x32_bf16(a, b, c, 0, 0, 0)
#define MFMAH(a,b,c) __builtin_amdgcn_mfma_f32_16x16x32_f16(a, b, c, 0, 0, 0)
#define WAVE_BAR() __builtin_amdgcn_wave_barrier()

__device__ __forceinline__ unsigned short f2bf(float f) {
    unsigned u = __builtin_bit_cast(unsigned, f);
    unsigned r = (u + 0x7FFFu + ((u >> 16) & 1u)) >> 16;   // RNE
    return (unsigned short)r;
}
__device__ __forceinline__ unsigned cvt_pk_bf16(float lo, float hi) {
    unsigned r;
    asm("v_cvt_pk_bf16_f32 %0, %1, %2" : "=v"(r) : "v"(lo), "v"(hi));
    return r;
}
__device__ __forceinline__ unsigned short f2h(float f) {
    _Float16 h = (_Float16)f;                              // v_cvt_f16_f32
    return __builtin_bit_cast(unsigned short, h);
}
__device__ __forceinline__ float ssp_f(float x) {
    return fmaxf(x, 0.0f) + __logf(1.0f + __expf(-fabsf(x))) - LOG2F_;
}

// ---------- prep: weights -> bf16 (w2c -> f16), transposed to [col][k] ----------
extern "C" __global__ __launch_bounds__(256)
void k_prep(const float* __restrict__ w1, const float* __restrict__ w2,
            const float* __restrict__ cl1, const float* __restrict__ w2c,
            const float* __restrict__ wi, const float* __restrict__ wl,
            ushort_t* __restrict__ w1T, ushort_t* __restrict__ w2T,
            ushort_t* __restrict__ cl1T, ushort_t* __restrict__ w2cT,
            ushort_t* __restrict__ wiT, ushort_t* __restrict__ wlT)
{
    int id = blockIdx.x * 256 + threadIdx.x;
    int stride = gridDim.x * 256;
    for (int i = id; i < 64*64;   i += stride){ int c=i>>6, k=i&63;  w1T[i]  = f2bf(k < NGAUSS ? w1[k*64+c] : 0.0f); }
    for (int i = id; i < 64*64;   i += stride){ int c=i>>6, k=i&63;  w2T[i]  = f2bf(w2[k*64+c]); }
    for (int i = id; i < 64*128;  i += stride){ int c=i>>7, k=i&127; cl1T[i] = f2bf(cl1[k*64+c]); }
    for (int i = id; i < 128*64;  i += stride){ int c=i>>6, k=i&63;  w2cT[i] = f2h(w2c[k*128+c]); }   // f16 (pairs with f16 agg)
    for (int i = id; i < 128*128; i += stride){ int c=i>>7, k=i&127; wiT[i]  = f2bf(wi[k*128+c]); }
    for (int i = id; i < 128*128; i += stride){ int c=i>>7, k=i&127; wlT[i]  = f2bf(wl[k*128+c]); }
}

// ---------- h = x @ conv_lin1_w -> f16, MFMA, wave = 32 rows ----------
// Also zeroes agg (f16) for this block's rows.
extern "C" __global__ __launch_bounds__(256)
void k_lin1_mfma(const float* __restrict__ x, const ushort_t* __restrict__ cl1T,
                 ushort_t* __restrict__ h16, ushort_t* __restrict__ agg16, int N)
{
    {
        int nb = blockIdx.x * 128;
        int rows = min(128, N - nb);
        if (rows > 0) {
            float4* ap = (float4*)(agg16 + (size_t)nb * NF);
            int tot = rows * (NF * 2 / 16);       // rows * 8 float4s
            for (int i = threadIdx.x; i < tot; i += 256)
                ap[i] = (float4){0,0,0,0};
        }
    }

    int l = threadIdx.x & 63, w = threadIdx.x >> 6;
    int base = (blockIdx.x * 4 + w) * 32;
    int colb = l & 15, krow = (l >> 4) * 8;

    v4f C[2][4];
    #pragma unroll
    for (int m = 0; m < 2; m++)
        #pragma unroll
        for (int n = 0; n < 4; n++) C[m][n] = (v4f){0,0,0,0};

    #pragma unroll
    for (int kt = 0; kt < 4; kt++) {
        v8s am[2];
        #pragma unroll
        for (int m = 0; m < 2; m++) {
            int row = base + m*16 + colb;
            union { v8s v; unsigned d[4]; } A;
            A.d[0]=0; A.d[1]=0; A.d[2]=0; A.d[3]=0;
            if (row < N) {
                const float4* p = (const float4*)(x + (size_t)row*DIM + kt*32 + krow);
                float4 f0 = p[0], f1 = p[1];
                A.d[0] = cvt_pk_bf16(f0.x, f0.y);
                A.d[1] = cvt_pk_bf16(f0.z, f0.w);
                A.d[2] = cvt_pk_bf16(f1.x, f1.y);
                A.d[3] = cvt_pk_bf16(f1.z, f1.w);
            }
            am[m] = A.v;
        }
        #pragma unroll
        for (int n = 0; n < 4; n++) {
            v8s b = *(const v8s*)(cl1T + (n*16 + colb)*DIM + kt*32 + krow);
            #pragma unroll
            for (int m = 0; m < 2; m++) C[m][n] = MFMA(am[m], b, C[m][n]);
        }
    }
    #pragma unroll
    for (int m = 0; m < 2; m++)
        #pragma unroll
        for (int n = 0; n < 4; n++)
            #pragma unroll
            for (int i = 0; i < 4; i++) {
                int row = base + m*16 + (l>>4)*4 + i;
                if (row < N) h16[(size_t)row*NF + n*16 + colb] = f2h(C[m][n][i]);
            }
}

// ---------- edge kernel: MFMA MLP + split-phase packed-f16 atomic scatter ----------
extern "C" __global__ __launch_bounds__(256)
void k_edge_mfma(const float* __restrict__ pos, const int* __restrict__ ei,
                 const ushort_t* __restrict__ h16,
                 const ushort_t* __restrict__ w1T, const ushort_t* __restrict__ w2T,
                 const float* __restrict__ b1, const float* __restrict__ b2,
                 ushort_t* __restrict__ agg16, int E)
{
    __shared__ __align__(16) char lds[4][64*128];   // per-wave 64x64 x16bit, XOR-swizzled
    int l = threadIdx.x & 63, w = threadIdx.x >> 6;
    char* T = lds[w];
    size_t ebase = ((size_t)blockIdx.x * 4 + w) * 64;
    int e = (int)(ebase + l);
    bool valid = e < E;
    int s = valid ? ei[e] : 0;
    int d = valid ? ei[E + e] : 0;

    float dx = pos[3*d]   - pos[3*s];
    float dy = pos[3*d+1] - pos[3*s+1];
    float dz = pos[3*d+2] - pos[3*s+2];
    float dist = sqrtf(dx*dx + dy*dy + dz*dz);
    float Cc = valid ? 0.5f * (__cosf(dist * PIC) + 1.0f) : 0.0f;
    int cci = __builtin_bit_cast(int, Cc);

    int colb = l & 15, krow = (l >> 4) * 8;

    float b1v[4], b2v[4];
    #pragma unroll
    for (int n = 0; n < 4; n++) { b1v[n] = b1[n*16 + colb]; b2v[n] = b2[n*16 + colb]; }

    // layer 1: ea (chain-exp, built directly in A-frag layout) @ w1
    v4f C1[4][4];
    #pragma unroll
    for (int m = 0; m < 4; m++)
        #pragma unroll
        for (int n = 0; n < 4; n++) C1[m][n] = (v4f){0,0,0,0};
    {
        v8s B1[2][4];
        #pragma unroll
        for (int n = 0; n < 4; n++)
            #pragma unroll
            for (int kt = 0; kt < 2; kt++)
                B1[kt][n] = *(const v8s*)(w1T + (n*16 + colb)*64 + kt*32 + krow);

        #pragma unroll
        for (int m = 0; m < 4; m++) {
            float dm = __shfl(dist, m*16 + colb);
            #pragma unroll
            for (int kt = 0; kt < 2; kt++) {
                int m0 = kt*32 + krow;
                float t0 = dm - (float)m0 * GSTEP;
                float e0 = __expf(GCOEFF * t0 * t0);
                float u  = __expf(fmaf(dm, INV_STEP, -((float)m0 + 0.5f)));
                float e1 = e0 * u; u *= EM1;
                float e2 = e1 * u; u *= EM1;
                float e3 = e2 * u; u *= EM1;
                float e4 = e3 * u; u *= EM1;
                float e5 = e4 * u; u *= EM1;
                float e6 = e5 * u; u *= EM1;
                float e7 = e6 * u;
                union { v8s v; unsigned dw[4]; } A;
                A.dw[0] = cvt_pk_bf16(e0, e1);
                A.dw[1] = cvt_pk_bf16(e2, e3);
                A.dw[2] = cvt_pk_bf16(e4, e5);
                A.dw[3] = cvt_pk_bf16(e6, e7);
                #pragma unroll
                for (int n = 0; n < 4; n++) C1[m][n] = MFMA(A.v, B1[kt][n], C1[m][n]);
            }
        }
    }

    // ssp -> bf16 -> swizzled LDS tile (row=edge, col=j1)
    #pragma unroll
    for (int m = 0; m < 4; m++)
        #pragma unroll
        for (int n = 0; n < 4; n++)
            #pragma unroll
            for (int i = 0; i < 4; i++) {
                int row = m*16 + (l>>4)*4 + i;
                int col = n*16 + colb;
                float v = ssp_f(C1[m][n][i] + b1v[n]);
                *(ushort_t*)(T + row*128 + ((col*2) ^ ((row&7)<<4))) = f2bf(v);
            }
    WAVE_BAR();

    // layer 2: hid @ w2
    v4f C2[4][4];
    #pragma unroll
    for (int m = 0; m < 4; m++)
        #pragma unroll
        for (int n = 0; n < 4; n++) C2[m][n] = (v4f){0,0,0,0};
    {
        v8s B2[2][4];
        #pragma unroll
        for (int n = 0; n < 4; n++)
            #pragma unroll
            for (int kt = 0; kt < 2; kt++)
                B2[kt][n] = *(const v8s*)(w2T + (n*16 + colb)*64 + kt*32 + krow);

        #pragma unroll
        for (int m = 0; m < 4; m++) {
            int row = m*16 + colb;
            #pragma unroll
            for (int kt = 0; kt < 2; kt++) {
                v8s a = *(const v8s*)(T + row*128 + ((kt*64 + krow*2) ^ ((row&7)<<4)));
                #pragma unroll
                for (int n = 0; n < 4; n++) C2[m][n] = MFMA(a, B2[kt][n], C2[m][n]);
            }
        }
    }
    WAVE_BAR();   // all layer-2 reads precede the W overwrite below (WAR)

    // W = C2 + b2 -> f16 -> same tile (Cc folded into scatter)
    #pragma unroll
    for (int m = 0; m < 4; m++)
        #pragma unroll
        for (int n = 0; n < 4; n++)
            #pragma unroll
            for (int i = 0; i < 4; i++) {
                int row = m*16 + (l>>4)*4 + i;
                int col = n*16 + colb;
                *(ushort_t*)(T + row*128 + ((col*2) ^ ((row&7)<<4))) = f2h(C2[m][n][i] + b2v[n]);
            }
    WAVE_BAR();

    // ---- scatter, split-phase ----
    // Phase 1: issue ALL h16 gathers + ALL LDS W-reads into named registers
    // (statically indexed; C1/C2's dead regs get reused). No waits interleave
    // with the atomics then.
    int jj = l & 31;
    int hsel = l >> 5;                       // 0: even edge, 1: odd edge
    unsigned hreg[32], wreg[32];
    #pragma unroll
    for (int e2 = 0; e2 < 32; e2++) {
        int sA = __builtin_amdgcn_readlane(s, 2*e2);
        int sB = __builtin_amdgcn_readlane(s, 2*e2 + 1);
        int ssel = hsel ? sB : sA;
        hreg[e2] = *(const unsigned*)(h16 + (size_t)ssel*NF + 2*jj);
        int epair = 2*e2 + hsel;
        wreg[e2] = *(const unsigned*)(T + epair*128 + ((jj*4) ^ ((epair&7)<<4)));
    }
    // Phase 2: pure atomic stream — register operands only, fire-and-forget.
    #pragma unroll
    for (int e2 = 0; e2 < 32; e2++) {
        int dA = __builtin_amdgcn_readlane(d, 2*e2);
        int dB = __builtin_amdgcn_readlane(d, 2*e2 + 1);
        int cA = __builtin_amdgcn_readlane(cci, 2*e2);
        int cB = __builtin_amdgcn_readlane(cci, 2*e2 + 1);
        int dsel = hsel ? dB : dA;
        float csel = __builtin_bit_cast(float, hsel ? cB : cA);

        __half2 wv = __builtin_bit_cast(__half2, wreg[e2]);
        __half2 hv = __builtin_bit_cast(__half2, hreg[e2]);
        __half ch = __float2half(csel);
        __half2 cv = __halves2half2(ch, ch);
        __half2 prod = __hmul2(__hmul2(wv, hv), cv);
        unsafeAtomicAdd((__half2*)(agg16 + (size_t)dsel*NF + 2*jj), prod);
    }
}

// ---------- fused tail, MFMA, wave = 32 rows ----------
extern "C" __global__ __launch_bounds__(256)
void k_tail_mfma(const float* __restrict__ x, const ushort_t* __restrict__ agg16,
                 const ushort_t* __restrict__ w2cT, const float* __restrict__ b2c,
                 const ushort_t* __restrict__ wiT,  const float* __restrict__ bi,
                 const ushort_t* __restrict__ wlT,  const float* __restrict__ bl,
                 float* __restrict__ out, int N)
{
    __shared__ __align__(16) char lds[4][32*256];   // per-wave 32x128 bf16, XOR-swizzled
    int l = threadIdx.x & 63, w = threadIdx.x >> 6;
    char* T = lds[w];
    int base = (blockIdx.x * 4 + w) * 32;
    int colb = l & 15, krow = (l >> 4) * 8;

    float b2cv[8], biv[8], blv[8];
    #pragma unroll
    for (int n = 0; n < 8; n++) {
        b2cv[n] = b2c[n*16 + colb];
        biv[n]  = bi[n*16 + colb];
        blv[n]  = bl[n*16 + colb];
    }

    // stage A: agg[32,64](f16) @ w2cT(f16) -> ssp -> LDS  (f16 MFMA, no convert)
    v4f C[2][8];
    #pragma unroll
    for (int m = 0; m < 2; m++)
        #pragma unroll
        for (int n = 0; n < 8; n++) C[m][n] = (v4f){0,0,0,0};

    #pragma unroll
    for (int kt = 0; kt < 2; kt++) {
        v8h am[2];
        #pragma unroll
        for (int m = 0; m < 2; m++) {
            int row = base + m*16 + colb;
            v8h a = (v8h){0,0,0,0,0,0,0,0};
            if (row < N) a = *(const v8h*)(agg16 + (size_t)row*NF + kt*32 + krow);
            am[m] = a;
        }
        #pragma unroll
        for (int n = 0; n < 8; n++) {
            v8h b = *(const v8h*)(w2cT + (n*16 + colb)*64 + kt*32 + krow);
            #pragma unroll
            for (int m = 0; m < 2; m++) C[m][n] = MFMAH(am[m], b, C[m][n]);
        }
    }
    #pragma unroll
    for (int m = 0; m < 2; m++)
        #pragma unroll
        for (int n = 0; n < 8; n++)
            #pragma unroll
            for (int i = 0; i < 4; i++) {
                int rl = m*16 + (l>>4)*4 + i;
                int col = n*16 + colb;
                float v = ssp_f(C[m][n][i] + b2cv[n]);
                *(ushort_t*)(T + rl*256 + ((col*2) ^ ((rl&7)<<4))) = f2bf(v);
            }
    WAVE_BAR();

    // stage B: h2[32,128] @ wiT
    v4f D[2][8];
    #pragma unroll
    for (int m = 0; m < 2; m++)
        #pragma unroll
        for (int n = 0; n < 8; n++) D[m][n] = (v4f){0,0,0,0};

    v8s af[2][4];
    #pragma unroll
    for (int m = 0; m < 2; m++)
        #pragma unroll
        for (int kt = 0; kt < 4; kt++) {
            int rl = m*16 + colb;
            af[m][kt] = *(const v8s*)(T + rl*256 + ((kt*64 + krow*2) ^ ((rl&7)<<4)));
        }
    #pragma unroll
    for (int kt = 0; kt < 4; kt++)
        #pragma unroll
        for (int n = 0; n < 8; n++) {
            v8s b = *(const v8s*)(wiT + (n*16 + colb)*DIM + kt*32 + krow);
            #pragma unroll
            for (int m = 0; m < 2; m++) D[m][n] = MFMA(af[m][kt], b, D[m][n]);
        }
    WAVE_BAR();
    #pragma unroll
    for (int m = 0; m < 2; m++)
        #pragma unroll
        for (int n = 0; n < 8; n++)
            #pragma unroll
            for (int i = 0; i < 4; i++) {
                int rl = m*16 + (l>>4)*4 + i;
                int col = n*16 + colb;
                *(ushort_t*)(T + rl*256 + ((col*2) ^ ((rl&7)<<4))) = f2bf(D[m][n][i] + biv[n]);
            }
    WAVE_BAR();

    // stage C: h3[32,128] @ wlT -> relu -> +x -> out
    v4f G[2][8];
    #pragma unroll
    for (int m = 0; m < 2; m++)
        #pragma unroll
        for (int n = 0; n < 8; n++) G[m][n] = (v4f){0,0,0,0};

    #pragma unroll
    for (int m = 0; m < 2; m++)
        #pragma unroll
        for (int kt = 0; kt < 4; kt++) {
            int rl = m*16 + colb;
            af[m][kt] = *(const v8s*)(T + rl*256 + ((kt*64 + krow*2) ^ ((rl&7)<<4)));
        }
    #pragma unroll
    for (int kt = 0; kt < 4; kt++)
        #pragma unroll
        for (int n = 0; n < 8; n++) {
            v8s b = *(const v8s*)(wlT + (n*16 + colb)*DIM + kt*32 + krow);
            #pragma unroll
            for (int m = 0; m < 2; m++) G[m][n] = MFMA(af[m][kt], b, G[m][n]);
        }

    #pragma unroll
    for (int m = 0; m < 2; m++)
        #pragma unroll
        for (int n = 0; n < 8; n++)
            #pragma unroll
            for (int i = 0; i < 4; i++) {
                int row = base + m*16 + (l>>4)*4 + i;
                if (row < N) {
                    int col = n*16 + colb;
                    size_t o = (size_t)row*DIM + col;
                    out[o] = x[o] + fmaxf(G[m][n][i] + blv[n], 0.0f);
                }
            }
}

extern "C" void kernel_launch(void* const* d_in, const int* in_sizes, int n_in,
                              void* d_out, int out_size, void* d_ws, size_t ws_size,
                              hipStream_t stream)
{
    const float* x    = (const float*)d_in[0];
    const float* pos  = (const float*)d_in[1];
    const int*   ei   = (const int*)  d_in[2];
    const float* mw1  = (const float*)d_in[3];
    const float* mb1  = (const float*)d_in[4];
    const float* mw2  = (const float*)d_in[5];
    const float* mb2  = (const float*)d_in[6];
    const float* cl1  = (const float*)d_in[7];
    const float* cl2  = (const float*)d_in[8];
    const float* cl2b = (const float*)d_in[9];
    const float* iw   = (const float*)d_in[10];
    const float* ib   = (const float*)d_in[11];
    const float* lw   = (const float*)d_in[12];
    const float* lb   = (const float*)d_in[13];
    float* out = (float*)d_out;

    int N = in_sizes[0] / DIM;
    int E = in_sizes[2] / 2;

    char* W = (char*)d_ws;
    size_t h_bytes   = (size_t)N * NF * sizeof(ushort_t);
    size_t agg_bytes = (size_t)N * NF * sizeof(ushort_t);
    ushort_t* h16   = (ushort_t*)W;
    ushort_t* agg16 = (ushort_t*)(W + h_bytes);
    ushort_t* wT    = (ushort_t*)(W + h_bytes + agg_bytes);
    ushort_t* w1T  = wT;
    ushort_t* w2T  = wT + 4096;
    ushort_t* cl1T = wT + 8192;
    ushort_t* w2cT = wT + 16384;
    ushort_t* wiT  = wT + 24576;
    ushort_t* wlT  = wT + 40960;

    k_prep<<<60, 256, 0, stream>>>(mw1, mw2, cl1, cl2, iw, lw,
                                   w1T, w2T, cl1T, w2cT, wiT, wlT);

    k_lin1_mfma<<<(N + 127) / 128, 256, 0, stream>>>(x, cl1T, h16, agg16, N);

    int ewaves = (E + 63) / 64;
    k_edge_mfma<<<(ewaves + 3) / 4, 256, 0, stream>>>(pos, ei, h16, w1T, w2T,
                                                      mb1, mb2, agg16, E);

    k_tail_mfma<<<(N + 127) / 128, 256, 0, stream>>>(x, agg16, w2cT, cl2b,
                                                     wiT, ib, wlT, lb, out, N);
}